// Round 5
// baseline (413.588 us; speedup 1.0000x reference)
//
#include <hip/hip_runtime.h>
#include <math.h>

#define N_NODES 50000
#define N_EDGES 1600000
#define D1 128
#define D2 40
#define D2P 48                    // padded G row
#define BROWS 128                 // rows per bucket
#define NB 391                    // ceil(N_NODES/BROWS)
#define CHUNK 6250                // N_EDGES / 256 (exact)

typedef __attribute__((ext_vector_type(8))) short bf16x8;
typedef __attribute__((ext_vector_type(4))) float f32x4;

// split f32 -> bf16 hi + bf16 lo (RNE both); x ~= hi + lo with ~2^-16 rel err
__device__ __forceinline__ void bf16_split(float v, unsigned short& h, unsigned short& l) {
    unsigned u = __float_as_uint(v);
    unsigned r = u + 0x7fffu + ((u >> 16) & 1u);
    h = (unsigned short)(r >> 16);
    float hf = __uint_as_float((unsigned)h << 16);
    float lof = v - hf;
    unsigned u2 = __float_as_uint(lof);
    unsigned r2 = u2 + 0x7fffu + ((u2 >> 16) & 1u);
    l = (unsigned short)(r2 >> 16);
}

__device__ __forceinline__ int edge_row(const unsigned int* ei, int e, int is64) {
    return (int)(is64 ? ei[2 * e] : ei[e]);
}
__device__ __forceinline__ int edge_col(const unsigned int* ei, int e, int is64) {
    return (int)(is64 ? ei[2 * (N_EDGES + e)] : ei[N_EDGES + e]);
}

// ---------------------------------------------------------------------------
// setup: block 0 = int64 detect; blocks 1..25 = zero gbhp; blocks 26..89 = pack W1.
__global__ __launch_bounds__(256) void setup_k(const unsigned int* __restrict__ ei,
                                               int* __restrict__ flag,
                                               unsigned int* __restrict__ gbhp,
                                               const float* __restrict__ W1,
                                               unsigned short* __restrict__ wh,
                                               unsigned short* __restrict__ wl) {
    int b = blockIdx.x, t = threadIdx.x;
    if (b == 0) {
        __shared__ int any;
        if (t == 0) any = 0;
        __syncthreads();
        for (int i = t; i < 2048; i += 256) {
            if (ei[2 * i + 1] != 0u) any = 1;
        }
        __syncthreads();
        if (t == 0) flag[0] = any ? 0 : 1;  // 1 == int64 layout
    } else if (b <= 25) {
        int i = (b - 1) * 256 + t;
        if (i < NB * 16) gbhp[i] = 0u;
    } else {
        int idx = (b - 26) * 256 + t;  // 16384 = 64 blocks
        int k = idx >> 7, n = idx & 127;
        unsigned short h, l;
        bf16_split(W1[k * 128 + n], h, l);
        int nt = n >> 4, ks = k >> 5;
        int lane = (n & 15) | (((k >> 3) & 3) << 4);
        int j = k & 7;
        int dst = ((nt * 4 + ks) * 64 + lane) * 8 + j;
        wh[dst] = h;
        wl[dst] = l;
    }
}

// ---------------------------------------------------------------------------
// Bucket histogram (LDS-aggregated). gbhp padded: counter b at gbhp[b*16].
__global__ __launch_bounds__(256) void bhist_k(const unsigned int* __restrict__ ei,
                                               const int* __restrict__ flag,
                                               unsigned int* __restrict__ gbhp) {
    __shared__ unsigned int bh[NB];
    int is64 = flag[0];
    int t = threadIdx.x;
    for (int i = t; i < NB; i += 256) bh[i] = 0;
    __syncthreads();
    int e0 = blockIdx.x * CHUNK, e1 = e0 + CHUNK;
    for (int e = e0 + t; e < e1; e += 256) {
        atomicAdd(&bh[edge_row(ei, e, is64) >> 7], 1u);
    }
    __syncthreads();
    for (int i = t; i < NB; i += 256) {
        if (bh[i]) atomicAdd(&gbhp[i * 16], bh[i]);
    }
}

__global__ __launch_bounds__(512) void bscan_k(const unsigned int* __restrict__ gbhp,
                                               int* __restrict__ bbase,
                                               unsigned int* __restrict__ bcurp) {
    __shared__ unsigned int s[512];
    int t = threadIdx.x;
    unsigned int v = (t < NB) ? gbhp[t * 16] : 0u;
    s[t] = v;
    __syncthreads();
    for (int off = 1; off < 512; off <<= 1) {
        unsigned int add = (t >= off) ? s[t - off] : 0u;
        __syncthreads();
        s[t] += add;
        __syncthreads();
    }
    if (t < NB) {
        unsigned int excl = s[t] - v;
        bbase[t] = (int)excl;
        bcurp[t * 16] = excl;
    }
    if (t == NB - 1) bbase[NB] = (int)s[t];
}

// Phase 1: bin edges into bucket regions as packed 8B records.
// rec.x = (rlocal<<24) | col;  rec.y = w bits.
__global__ __launch_bounds__(256) void bin_k(const unsigned int* __restrict__ ei,
                                             const float* __restrict__ ew,
                                             const int* __restrict__ flag,
                                             unsigned int* __restrict__ bcurp,
                                             uint2* __restrict__ tmp8) {
    __shared__ unsigned int lh[NB];
    __shared__ unsigned int lcur[NB];
    int is64 = flag[0];
    int t = threadIdx.x;
    for (int i = t; i < NB; i += 256) lh[i] = 0;
    __syncthreads();
    int e0 = blockIdx.x * CHUNK, e1 = e0 + CHUNK;
    for (int e = e0 + t; e < e1; e += 256) {
        atomicAdd(&lh[edge_row(ei, e, is64) >> 7], 1u);
    }
    __syncthreads();
    for (int i = t; i < NB; i += 256) {
        if (lh[i]) lcur[i] = atomicAdd(&bcurp[i * 16], lh[i]);
    }
    __syncthreads();
    for (int e = e0 + t; e < e1; e += 256) {
        int r = edge_row(ei, e, is64);
        int c = edge_col(ei, e, is64);
        int b = r >> 7;
        unsigned int p = atomicAdd(&lcur[b], 1u);
        uint2 rec;
        rec.x = ((unsigned int)(r & 127) << 24) | (unsigned int)c;
        rec.y = __float_as_uint(ew[e]);
        tmp8[p] = rec;
    }
}

// Phase 2: per-bucket row counts -> rowptr, then in-window counting-sort scatter.
__global__ __launch_bounds__(256) void csr_k(const uint2* __restrict__ tmp8,
                                             const int* __restrict__ bbase,
                                             int* __restrict__ rowptr,
                                             uint2* __restrict__ colwS) {
    __shared__ unsigned int rcnt[BROWS];
    __shared__ unsigned int loff[BROWS];
    __shared__ unsigned int lcur[BROWS];
    int b = blockIdx.x;
    int t = threadIdx.x;
    int lo = bbase[b], hi = bbase[b + 1];
    int r0 = b * BROWS;
    int nrows = N_NODES - r0;
    if (nrows > BROWS) nrows = BROWS;
    if (t < BROWS) rcnt[t] = 0;
    __syncthreads();
    for (int j = lo + t; j < hi; j += 256) {
        atomicAdd(&rcnt[tmp8[j].x >> 24], 1u);
    }
    __syncthreads();
    if (t < BROWS) loff[t] = rcnt[t];
    __syncthreads();
    for (int off = 1; off < BROWS; off <<= 1) {
        unsigned int add = (t >= off && t < BROWS) ? loff[t - off] : 0u;
        __syncthreads();
        if (t < BROWS) loff[t] += add;
        __syncthreads();
    }
    if (t < BROWS) {
        unsigned int excl = loff[t] - rcnt[t];
        if (t < nrows) rowptr[r0 + t] = lo + (int)excl;
        lcur[t] = (unsigned int)lo + excl;
    }
    if (b == NB - 1 && t == 0) rowptr[N_NODES] = hi;
    __syncthreads();
    for (int j = lo + t; j < hi; j += 256) {
        uint2 rec = tmp8[j];
        unsigned int rl = rec.x >> 24;
        unsigned int p = atomicAdd(&lcur[rl], 1u);
        uint2 cw;
        cw.x = rec.x & 0xFFFFFFu;
        cw.y = rec.y;
        colwS[p] = cw;
    }
}

// ---------------------------------------------------------------------------
// A = x @ W1 via mfma_f32_16x16x32_bf16, split-bf16 3-pass (hh + hl + lh).
__global__ __launch_bounds__(256) void gemm1_k(const float* __restrict__ x,
                                               const unsigned short* __restrict__ wh,
                                               const unsigned short* __restrict__ wl,
                                               float* __restrict__ A) {
    int t = threadIdx.x;
    int w = t >> 6, l = t & 63;
    int row0 = blockIdx.x * 64 + w * 16;
    int arow = row0 + (l & 15);
    if (arow > N_NODES - 1) arow = N_NODES - 1;
    int kbase = (l >> 4) * 8;
    bf16x8 ah[4], al[4];
#pragma unroll
    for (int ks = 0; ks < 4; ++ks) {
        const float* px = &x[arow * D1 + ks * 32 + kbase];
        float4 v0 = *reinterpret_cast<const float4*>(px);
        float4 v1 = *reinterpret_cast<const float4*>(px + 4);
        float vv[8] = {v0.x, v0.y, v0.z, v0.w, v1.x, v1.y, v1.z, v1.w};
#pragma unroll
        for (int j = 0; j < 8; ++j) {
            unsigned short h, lo2;
            bf16_split(vv[j], h, lo2);
            ah[ks][j] = (short)h;
            al[ks][j] = (short)lo2;
        }
    }
    f32x4 acc[8];
#pragma unroll
    for (int nt = 0; nt < 8; ++nt) acc[nt] = (f32x4)(0.f);
#pragma unroll
    for (int nt = 0; nt < 8; ++nt) {
#pragma unroll
        for (int ks = 0; ks < 4; ++ks) {
            int fo = ((nt * 4 + ks) * 64 + l) * 8;
            bf16x8 bh = *reinterpret_cast<const bf16x8*>(&wh[fo]);
            bf16x8 bl = *reinterpret_cast<const bf16x8*>(&wl[fo]);
            acc[nt] = __builtin_amdgcn_mfma_f32_16x16x32_bf16(ah[ks], bh, acc[nt], 0, 0, 0);
            acc[nt] = __builtin_amdgcn_mfma_f32_16x16x32_bf16(ah[ks], bl, acc[nt], 0, 0, 0);
            acc[nt] = __builtin_amdgcn_mfma_f32_16x16x32_bf16(al[ks], bh, acc[nt], 0, 0, 0);
        }
    }
    int crow0 = row0 + (l >> 4) * 4;
    int ccol = l & 15;
#pragma unroll
    for (int nt = 0; nt < 8; ++nt) {
#pragma unroll
        for (int r = 0; r < 4; ++r) {
            int rr = crow0 + r;
            if (rr < N_NODES) A[rr * D1 + nt * 16 + ccol] = acc[nt][r];
        }
    }
}

// ---------------------------------------------------------------------------
// Fused: G[r] = relu(sum_j w_j*A[col_j] + b1) @ W2  (one row per wave).
// Gather phase: half-wave processes 8 edges per iteration; one 64B vector load
// prefetches 8 edge records, 8 independent 512B gathers follow (MLP ~16/wave).
// Dot phase: lane c (<48) does g = sum_k shfl-broadcast(h[k]) * W2lds[k][c].
__global__ __launch_bounds__(256) void spmm1g_k(const float* __restrict__ A,
                                                const int* __restrict__ rowptr,
                                                const uint2* __restrict__ colwS,
                                                const float* __restrict__ b1,
                                                const float* __restrict__ W2,
                                                float* __restrict__ G) {
    __shared__ float w2s[128][D2P];
    int t = threadIdx.x;
    for (int i = t; i < 128 * D2P; i += 256) {
        int k = i / D2P, c = i % D2P;
        w2s[k][c] = (c < D2) ? W2[k * D2 + c] : 0.f;
    }
    __syncthreads();
    int r = blockIdx.x * 4 + (t >> 6);
    int lane = t & 63;
    int half = lane >> 5;
    int cg = lane & 31;
    int s = rowptr[r], e = rowptr[r + 1];
    float4 acc = {0.f, 0.f, 0.f, 0.f};
    for (int j0 = s + half * 8; j0 < e; j0 += 16) {
        uint2 cwv = colwS[min(j0 + (lane & 7), e - 1)];
        int nn = e - j0;  // uniform per half
#pragma unroll
        for (int k = 0; k < 8; ++k) {
            if (k < nn) {
                int srcl = (half << 5) + k;
                unsigned cx = __shfl(cwv.x, srcl);
                float wv = __uint_as_float(__shfl(cwv.y, srcl));
                float4 v = *reinterpret_cast<const float4*>(&A[cx * D1 + cg * 4]);
                acc.x += wv * v.x;
                acc.y += wv * v.y;
                acc.z += wv * v.z;
                acc.w += wv * v.w;
            }
        }
    }
    acc.x += __shfl_xor(acc.x, 32);
    acc.y += __shfl_xor(acc.y, 32);
    acc.z += __shfl_xor(acc.z, 32);
    acc.w += __shfl_xor(acc.w, 32);
    // bias + relu (both halves hold the full combined row now)
    float4 bv = *reinterpret_cast<const float4*>(&b1[cg * 4]);
    float h0 = fmaxf(acc.x + bv.x, 0.f);
    float h1 = fmaxf(acc.y + bv.y, 0.f);
    float h2 = fmaxf(acc.z + bv.z, 0.f);
    float h3 = fmaxf(acc.w + bv.w, 0.f);
    if (lane < D2P) {
        float g = 0.f;
#pragma unroll
        for (int k = 0; k < 128; ++k) {
            int srcl = k >> 2;  // lanes 0..31 hold h
            float hk;
            switch (k & 3) {
                case 0: hk = __shfl(h0, srcl); break;
                case 1: hk = __shfl(h1, srcl); break;
                case 2: hk = __shfl(h2, srcl); break;
                default: hk = __shfl(h3, srcl); break;
            }
            g += hk * w2s[k][lane];
        }
        G[r * D2P + lane] = g;
    }
}

// out[r] = log_softmax(sum_j w_j * G[col_j] + b2) — one wave per row.
// 4 slots x 12 lanes (float4 each over padded 48 cols); 4-edge record prefetch.
__global__ __launch_bounds__(256) void spmm2lsm_k(const float* __restrict__ G,
                                                  const int* __restrict__ rowptr,
                                                  const uint2* __restrict__ colwS,
                                                  const float* __restrict__ b2,
                                                  float* __restrict__ out) {
    int t = threadIdx.x;
    int r = blockIdx.x * 4 + (t >> 6);
    int lane = t & 63;
    int slot = lane / 12;   // 0..3 active (lanes 0..47)
    int g4 = lane % 12;     // float4 group: cols g4*4..g4*4+3
    int s = rowptr[r], e = rowptr[r + 1];
    float4 acc = {0.f, 0.f, 0.f, 0.f};
    bool act = lane < 48;
#pragma unroll 2
    for (int j0 = s; j0 < e; j0 += 4) {
        uint2 cwv = colwS[min(j0 + (lane & 3), e - 1)];
        if (act && j0 + slot < e) {
            unsigned cx = __shfl(cwv.x, slot);
            float wv = __uint_as_float(__shfl(cwv.y, slot));
            float4 v = *reinterpret_cast<const float4*>(&G[cx * D2P + g4 * 4]);
            acc.x += wv * v.x;
            acc.y += wv * v.y;
            acc.z += wv * v.z;
            acc.w += wv * v.w;
        }
    }
    // slot reduce: lanes 0..11 <- s0+s1+s2+s3
    acc.x += __shfl_down(acc.x, 24);
    acc.y += __shfl_down(acc.y, 24);
    acc.z += __shfl_down(acc.z, 24);
    acc.w += __shfl_down(acc.w, 24);
    acc.x += __shfl_down(acc.x, 12);
    acc.y += __shfl_down(acc.y, 12);
    acc.z += __shfl_down(acc.z, 12);
    acc.w += __shfl_down(acc.w, 12);
    bool valid = lane < 10;
    float4 v4 = {-INFINITY, -INFINITY, -INFINITY, -INFINITY};
    if (valid) {
        float4 bv = *reinterpret_cast<const float4*>(&b2[lane * 4]);
        v4.x = acc.x + bv.x;
        v4.y = acc.y + bv.y;
        v4.z = acc.z + bv.z;
        v4.w = acc.w + bv.w;
    }
    float m = fmaxf(fmaxf(v4.x, v4.y), fmaxf(v4.z, v4.w));
#pragma unroll
    for (int off = 1; off < 16; off <<= 1) m = fmaxf(m, __shfl_xor(m, off));
    float ex = valid ? expf(v4.x - m) + expf(v4.y - m) + expf(v4.z - m) + expf(v4.w - m) : 0.f;
#pragma unroll
    for (int off = 1; off < 16; off <<= 1) ex += __shfl_xor(ex, off);
    float lse = m + logf(ex);
    if (valid) {
        float4 o;
        o.x = v4.x - lse;
        o.y = v4.y - lse;
        o.z = v4.z - lse;
        o.w = v4.w - lse;
        *reinterpret_cast<float4*>(&out[r * D2 + lane * 4]) = o;
    }
}

// ---------------------------------------------------------------------------
extern "C" void kernel_launch(void* const* d_in, const int* in_sizes, int n_in,
                              void* d_out, int out_size, void* d_ws, size_t ws_size,
                              hipStream_t stream) {
    const float* x = (const float*)d_in[0];
    const unsigned int* ei = (const unsigned int*)d_in[1];
    const float* ew = (const float*)d_in[2];
    const float* W1 = (const float*)d_in[3];
    const float* b1 = (const float*)d_in[4];
    const float* W2 = (const float*)d_in[5];
    const float* b2 = (const float*)d_in[6];
    float* out = (float*)d_out;

    char* w = (char*)d_ws;
    float* A = (float*)w;                                   // 25.6 MB  x@W1
    float* G = (float*)(w + 25600000);                      // 9.6 MB   [N][48]
    uint2* tmp8 = (uint2*)(w + 35200000);                   // 12.8 MB
    uint2* colwS = (uint2*)(w + 48000000);                  // 12.8 MB
    int* rowptr = (int*)(w + 60800000);                     // (N+1)*4
    int* bbase = (int*)(w + 61000064);                      // (NB+1)*4
    unsigned int* bcurp = (unsigned int*)(w + 61001664);    // NB*64
    unsigned int* gbhp = (unsigned int*)(w + 61026688);     // NB*64
    int* flag = (int*)(w + 61051712);                       // 4
    unsigned short* wh1 = (unsigned short*)(w + 61051776);  // 32 KB
    unsigned short* wl1 = (unsigned short*)(w + 61084544);  // 32 KB

    setup_k<<<90, 256, 0, stream>>>(ei, flag, gbhp, W1, wh1, wl1);
    bhist_k<<<256, 256, 0, stream>>>(ei, flag, gbhp);
    bscan_k<<<1, 512, 0, stream>>>(gbhp, bbase, bcurp);
    bin_k<<<256, 256, 0, stream>>>(ei, ew, flag, bcurp, tmp8);
    csr_k<<<NB, 256, 0, stream>>>(tmp8, bbase, rowptr, colwS);

    gemm1_k<<<782, 256, 0, stream>>>(x, wh1, wl1, A);
    spmm1g_k<<<N_NODES / 4, 256, 0, stream>>>(A, rowptr, colwS, b1, W2, G);
    spmm2lsm_k<<<N_NODES / 4, 256, 0, stream>>>(G, rowptr, colwS, b2, out);
}

// Round 6
// 277.823 us; speedup vs baseline: 1.4887x; 1.4887x over previous
//
#include <hip/hip_runtime.h>
#include <hip/hip_fp16.h>
#include <math.h>

#define N_NODES 50000
#define N_EDGES 1600000
#define D1 128
#define D2 40
#define D2P 48                    // padded G row (f32), 192 B = 3 lines
#define BROWS 128                 // rows per bucket
#define NB 391                    // ceil(N_NODES/BROWS)
#define CHUNK 6250                // N_EDGES / 256 (exact)

typedef __attribute__((ext_vector_type(8))) short bf16x8;
typedef __attribute__((ext_vector_type(4))) float f32x4;

// split f32 -> bf16 hi + bf16 lo (RNE both); x ~= hi + lo with ~2^-16 rel err
__device__ __forceinline__ void bf16_split(float v, unsigned short& h, unsigned short& l) {
    unsigned u = __float_as_uint(v);
    unsigned r = u + 0x7fffu + ((u >> 16) & 1u);
    h = (unsigned short)(r >> 16);
    float hf = __uint_as_float((unsigned)h << 16);
    float lof = v - hf;
    unsigned u2 = __float_as_uint(lof);
    unsigned r2 = u2 + 0x7fffu + ((u2 >> 16) & 1u);
    l = (unsigned short)(r2 >> 16);
}

__device__ __forceinline__ int edge_row(const unsigned int* ei, int e, int is64) {
    return (int)(is64 ? ei[2 * e] : ei[e]);
}
__device__ __forceinline__ int edge_col(const unsigned int* ei, int e, int is64) {
    return (int)(is64 ? ei[2 * (N_EDGES + e)] : ei[N_EDGES + e]);
}

// ---------------------------------------------------------------------------
// setup: b0 = int64 detect; b1..25 zero gbhp; b26..89 pack W1; b90..113 pack W2.
__global__ __launch_bounds__(256) void setup_k(const unsigned int* __restrict__ ei,
                                               int* __restrict__ flag,
                                               unsigned int* __restrict__ gbhp,
                                               const float* __restrict__ W1,
                                               unsigned short* __restrict__ wh1,
                                               unsigned short* __restrict__ wl1,
                                               const float* __restrict__ W2,
                                               unsigned short* __restrict__ wh2,
                                               unsigned short* __restrict__ wl2) {
    int b = blockIdx.x, t = threadIdx.x;
    if (b == 0) {
        __shared__ int any;
        if (t == 0) any = 0;
        __syncthreads();
        for (int i = t; i < 2048; i += 256) {
            if (ei[2 * i + 1] != 0u) any = 1;
        }
        __syncthreads();
        if (t == 0) flag[0] = any ? 0 : 1;  // 1 == int64 layout
    } else if (b <= 25) {
        int i = (b - 1) * 256 + t;
        if (i < NB * 16) gbhp[i] = 0u;
    } else if (b <= 89) {
        int idx = (b - 26) * 256 + t;  // 16384
        int k = idx >> 7, n = idx & 127;
        unsigned short h, l;
        bf16_split(W1[k * 128 + n], h, l);
        int nt = n >> 4, ks = k >> 5;
        int lane = (n & 15) | (((k >> 3) & 3) << 4);
        int j = k & 7;
        int dst = ((nt * 4 + ks) * 64 + lane) * 8 + j;
        wh1[dst] = h;
        wl1[dst] = l;
    } else {
        int idx = (b - 90) * 256 + t;  // 6144
        if (idx < 128 * D2P) {
            int k = idx / D2P, n = idx % D2P;
            float v = (n < D2) ? W2[k * D2 + n] : 0.f;
            unsigned short h, l;
            bf16_split(v, h, l);
            int nt = n >> 4, ks = k >> 5;
            int lane = (n & 15) | (((k >> 3) & 3) << 4);
            int j = k & 7;
            int dst = ((nt * 4 + ks) * 64 + lane) * 8 + j;
            wh2[dst] = h;
            wl2[dst] = l;
        }
    }
}

// ---------------------------------------------------------------------------
__global__ __launch_bounds__(256) void bhist_k(const unsigned int* __restrict__ ei,
                                               const int* __restrict__ flag,
                                               unsigned int* __restrict__ gbhp) {
    __shared__ unsigned int bh[NB];
    int is64 = flag[0];
    int t = threadIdx.x;
    for (int i = t; i < NB; i += 256) bh[i] = 0;
    __syncthreads();
    int e0 = blockIdx.x * CHUNK, e1 = e0 + CHUNK;
    for (int e = e0 + t; e < e1; e += 256) {
        atomicAdd(&bh[edge_row(ei, e, is64) >> 7], 1u);
    }
    __syncthreads();
    for (int i = t; i < NB; i += 256) {
        if (bh[i]) atomicAdd(&gbhp[i * 16], bh[i]);
    }
}

__global__ __launch_bounds__(512) void bscan_k(const unsigned int* __restrict__ gbhp,
                                               int* __restrict__ bbase,
                                               unsigned int* __restrict__ bcurp) {
    __shared__ unsigned int s[512];
    int t = threadIdx.x;
    unsigned int v = (t < NB) ? gbhp[t * 16] : 0u;
    s[t] = v;
    __syncthreads();
    for (int off = 1; off < 512; off <<= 1) {
        unsigned int add = (t >= off) ? s[t - off] : 0u;
        __syncthreads();
        s[t] += add;
        __syncthreads();
    }
    if (t < NB) {
        unsigned int excl = s[t] - v;
        bbase[t] = (int)excl;
        bcurp[t * 16] = excl;
    }
    if (t == NB - 1) bbase[NB] = (int)s[t];
}

// Phase 1: bin edges into bucket regions as packed 8B records.
__global__ __launch_bounds__(256) void bin_k(const unsigned int* __restrict__ ei,
                                             const float* __restrict__ ew,
                                             const int* __restrict__ flag,
                                             unsigned int* __restrict__ bcurp,
                                             uint2* __restrict__ tmp8) {
    __shared__ unsigned int lh[NB];
    __shared__ unsigned int lcur[NB];
    int is64 = flag[0];
    int t = threadIdx.x;
    for (int i = t; i < NB; i += 256) lh[i] = 0;
    __syncthreads();
    int e0 = blockIdx.x * CHUNK, e1 = e0 + CHUNK;
    for (int e = e0 + t; e < e1; e += 256) {
        atomicAdd(&lh[edge_row(ei, e, is64) >> 7], 1u);
    }
    __syncthreads();
    for (int i = t; i < NB; i += 256) {
        if (lh[i]) lcur[i] = atomicAdd(&bcurp[i * 16], lh[i]);
    }
    __syncthreads();
    for (int e = e0 + t; e < e1; e += 256) {
        int r = edge_row(ei, e, is64);
        int c = edge_col(ei, e, is64);
        int b = r >> 7;
        unsigned int p = atomicAdd(&lcur[b], 1u);
        uint2 rec;
        rec.x = ((unsigned int)(r & 127) << 24) | (unsigned int)c;
        rec.y = __float_as_uint(ew[e]);
        tmp8[p] = rec;
    }
}

// Phase 2: per-bucket row counts -> rowptr, then in-window counting-sort scatter.
__global__ __launch_bounds__(256) void csr_k(const uint2* __restrict__ tmp8,
                                             const int* __restrict__ bbase,
                                             int* __restrict__ rowptr,
                                             uint2* __restrict__ colwS) {
    __shared__ unsigned int rcnt[BROWS];
    __shared__ unsigned int loff[BROWS];
    __shared__ unsigned int lcur[BROWS];
    int b = blockIdx.x;
    int t = threadIdx.x;
    int lo = bbase[b], hi = bbase[b + 1];
    int r0 = b * BROWS;
    int nrows = N_NODES - r0;
    if (nrows > BROWS) nrows = BROWS;
    if (t < BROWS) rcnt[t] = 0;
    __syncthreads();
    for (int j = lo + t; j < hi; j += 256) {
        atomicAdd(&rcnt[tmp8[j].x >> 24], 1u);
    }
    __syncthreads();
    if (t < BROWS) loff[t] = rcnt[t];
    __syncthreads();
    for (int off = 1; off < BROWS; off <<= 1) {
        unsigned int add = (t >= off && t < BROWS) ? loff[t - off] : 0u;
        __syncthreads();
        if (t < BROWS) loff[t] += add;
        __syncthreads();
    }
    if (t < BROWS) {
        unsigned int excl = loff[t] - rcnt[t];
        if (t < nrows) rowptr[r0 + t] = lo + (int)excl;
        lcur[t] = (unsigned int)lo + excl;
    }
    if (b == NB - 1 && t == 0) rowptr[N_NODES] = hi;
    __syncthreads();
    for (int j = lo + t; j < hi; j += 256) {
        uint2 rec = tmp8[j];
        unsigned int rl = rec.x >> 24;
        unsigned int p = atomicAdd(&lcur[rl], 1u);
        uint2 cw;
        cw.x = rec.x & 0xFFFFu;
        cw.y = rec.y;
        colwS[p] = cw;
    }
}

// ---------------------------------------------------------------------------
// A(fp16) = x @ W1 via mfma_f32_16x16x32_bf16, split-bf16 3-pass.
// fp16 output: halves gather bytes in spmm1 (the MSHR-bound hot kernel).
__global__ __launch_bounds__(256) void gemm1_k(const float* __restrict__ x,
                                               const unsigned short* __restrict__ wh,
                                               const unsigned short* __restrict__ wl,
                                               __half* __restrict__ Ah) {
    int t = threadIdx.x;
    int w = t >> 6, l = t & 63;
    int row0 = blockIdx.x * 64 + w * 16;
    int arow = row0 + (l & 15);
    if (arow > N_NODES - 1) arow = N_NODES - 1;
    int kbase = (l >> 4) * 8;
    bf16x8 ah[4], al[4];
#pragma unroll
    for (int ks = 0; ks < 4; ++ks) {
        const float* px = &x[arow * D1 + ks * 32 + kbase];
        float4 v0 = *reinterpret_cast<const float4*>(px);
        float4 v1 = *reinterpret_cast<const float4*>(px + 4);
        float vv[8] = {v0.x, v0.y, v0.z, v0.w, v1.x, v1.y, v1.z, v1.w};
#pragma unroll
        for (int j = 0; j < 8; ++j) {
            unsigned short h, lo2;
            bf16_split(vv[j], h, lo2);
            ah[ks][j] = (short)h;
            al[ks][j] = (short)lo2;
        }
    }
    f32x4 acc[8];
#pragma unroll
    for (int nt = 0; nt < 8; ++nt) acc[nt] = (f32x4)(0.f);
#pragma unroll
    for (int nt = 0; nt < 8; ++nt) {
#pragma unroll
        for (int ks = 0; ks < 4; ++ks) {
            int fo = ((nt * 4 + ks) * 64 + l) * 8;
            bf16x8 bh = *reinterpret_cast<const bf16x8*>(&wh[fo]);
            bf16x8 bl = *reinterpret_cast<const bf16x8*>(&wl[fo]);
            acc[nt] = __builtin_amdgcn_mfma_f32_16x16x32_bf16(ah[ks], bh, acc[nt], 0, 0, 0);
            acc[nt] = __builtin_amdgcn_mfma_f32_16x16x32_bf16(ah[ks], bl, acc[nt], 0, 0, 0);
            acc[nt] = __builtin_amdgcn_mfma_f32_16x16x32_bf16(al[ks], bh, acc[nt], 0, 0, 0);
        }
    }
    int crow0 = row0 + (l >> 4) * 4;
    int ccol = l & 15;
#pragma unroll
    for (int nt = 0; nt < 8; ++nt) {
#pragma unroll
        for (int r = 0; r < 4; ++r) {
            int rr = crow0 + r;
            if (rr < N_NODES) Ah[rr * D1 + nt * 16 + ccol] = __float2half_rn(acc[nt][r]);
        }
    }
}

// B[r] = sum_j w_j * A[col_j]  — one row/wave, half-wave per edge.
// fp16 rows: 256 B = 4 cache lines per edge (was 8) — attacks the per-CU
// miss-tracking ceiling identified in R4/R5 counters.
__global__ __launch_bounds__(256) void spmm1_k(const __half* __restrict__ Ah,
                                               const int* __restrict__ rowptr,
                                               const uint2* __restrict__ colwS,
                                               float* __restrict__ B) {
    int t = threadIdx.x;
    int r = blockIdx.x * 4 + (t >> 6);
    int lane = t & 63;
    int half = lane >> 5;
    int cg = lane & 31;
    int s = rowptr[r], e = rowptr[r + 1];
    float4 acc = {0.f, 0.f, 0.f, 0.f};
#pragma unroll 4
    for (int j = s + half; j < e; j += 2) {
        uint2 cw = colwS[j];
        float w = __uint_as_float(cw.y);
        uint2 q = *reinterpret_cast<const uint2*>(&Ah[cw.x * D1 + cg * 4]);
        float2 f0 = __half22float2(*reinterpret_cast<const __half2*>(&q.x));
        float2 f1 = __half22float2(*reinterpret_cast<const __half2*>(&q.y));
        acc.x += w * f0.x;
        acc.y += w * f0.y;
        acc.z += w * f1.x;
        acc.w += w * f1.y;
    }
    acc.x += __shfl_xor(acc.x, 32);
    acc.y += __shfl_xor(acc.y, 32);
    acc.z += __shfl_xor(acc.z, 32);
    acc.w += __shfl_xor(acc.w, 32);
    if (half == 0) *reinterpret_cast<float4*>(&B[r * D1 + cg * 4]) = acc;
}

// G[N][48] = relu(B + b1) @ W2 via MFMA split-bf16 (all 48 cols written; 40..47 = 0).
__global__ __launch_bounds__(256) void gemm2_k(const float* __restrict__ Bm,
                                               const float* __restrict__ b1,
                                               const unsigned short* __restrict__ wh,
                                               const unsigned short* __restrict__ wl,
                                               float* __restrict__ G) {
    int t = threadIdx.x;
    int w = t >> 6, l = t & 63;
    int row0 = blockIdx.x * 64 + w * 16;
    int arow = row0 + (l & 15);
    if (arow > N_NODES - 1) arow = N_NODES - 1;
    int kbase = (l >> 4) * 8;
    bf16x8 ah[4], al[4];
#pragma unroll
    for (int ks = 0; ks < 4; ++ks) {
        const float* pb = &Bm[arow * D1 + ks * 32 + kbase];
        const float* pb1 = &b1[ks * 32 + kbase];
        float4 v0 = *reinterpret_cast<const float4*>(pb);
        float4 v1 = *reinterpret_cast<const float4*>(pb + 4);
        float4 c0 = *reinterpret_cast<const float4*>(pb1);
        float4 c1 = *reinterpret_cast<const float4*>(pb1 + 4);
        float vv[8] = {v0.x + c0.x, v0.y + c0.y, v0.z + c0.z, v0.w + c0.w,
                       v1.x + c1.x, v1.y + c1.y, v1.z + c1.z, v1.w + c1.w};
#pragma unroll
        for (int j = 0; j < 8; ++j) {
            float rv = vv[j] > 0.f ? vv[j] : 0.f;
            unsigned short h, lo2;
            bf16_split(rv, h, lo2);
            ah[ks][j] = (short)h;
            al[ks][j] = (short)lo2;
        }
    }
    f32x4 acc[3];
#pragma unroll
    for (int nt = 0; nt < 3; ++nt) acc[nt] = (f32x4)(0.f);
#pragma unroll
    for (int nt = 0; nt < 3; ++nt) {
#pragma unroll
        for (int ks = 0; ks < 4; ++ks) {
            int fo = ((nt * 4 + ks) * 64 + l) * 8;
            bf16x8 bh = *reinterpret_cast<const bf16x8*>(&wh[fo]);
            bf16x8 bl = *reinterpret_cast<const bf16x8*>(&wl[fo]);
            acc[nt] = __builtin_amdgcn_mfma_f32_16x16x32_bf16(ah[ks], bh, acc[nt], 0, 0, 0);
            acc[nt] = __builtin_amdgcn_mfma_f32_16x16x32_bf16(ah[ks], bl, acc[nt], 0, 0, 0);
            acc[nt] = __builtin_amdgcn_mfma_f32_16x16x32_bf16(al[ks], bh, acc[nt], 0, 0, 0);
        }
    }
    int crow0 = row0 + (l >> 4) * 4;
    int ccol = l & 15;
#pragma unroll
    for (int nt = 0; nt < 3; ++nt) {
        int col = nt * 16 + ccol;
#pragma unroll
        for (int r = 0; r < 4; ++r) {
            int rr = crow0 + r;
            if (rr < N_NODES) G[rr * D2P + col] = acc[nt][r];
        }
    }
}

// out[r] = log_softmax(sum_j w_j * G[col_j] + b2) — one wave/row, 6 slots x 10 lanes.
__global__ __launch_bounds__(256) void spmm2lsm_k(const float* __restrict__ G,
                                                  const int* __restrict__ rowptr,
                                                  const uint2* __restrict__ colwS,
                                                  const float* __restrict__ b2,
                                                  float* __restrict__ out) {
    int t = threadIdx.x;
    int r = blockIdx.x * 4 + (t >> 6);
    int lane = t & 63;
    int slot = lane / 10;   // 0..5 active
    int comp = lane % 10;   // float4 group: cols comp*4..comp*4+3
    int s = rowptr[r], e = rowptr[r + 1];
    float4 acc = {0.f, 0.f, 0.f, 0.f};
    bool act = lane < 60;
#pragma unroll 2
    for (int j0 = s; j0 < e; j0 += 6) {
        int j = j0 + slot;
        if (act && j < e) {
            uint2 cw = colwS[j];
            float w = __uint_as_float(cw.y);
            float4 v = *reinterpret_cast<const float4*>(&G[cw.x * D2P + comp * 4]);
            acc.x += w * v.x;
            acc.y += w * v.y;
            acc.z += w * v.z;
            acc.w += w * v.w;
        }
    }
    acc.x += __shfl_down(acc.x, 30);
    acc.y += __shfl_down(acc.y, 30);
    acc.z += __shfl_down(acc.z, 30);
    acc.w += __shfl_down(acc.w, 30);
    {
        float t1 = __shfl_down(acc.x, 10), t2 = __shfl_down(acc.x, 20);
        acc.x += t1 + t2;
        t1 = __shfl_down(acc.y, 10); t2 = __shfl_down(acc.y, 20);
        acc.y += t1 + t2;
        t1 = __shfl_down(acc.z, 10); t2 = __shfl_down(acc.z, 20);
        acc.z += t1 + t2;
        t1 = __shfl_down(acc.w, 10); t2 = __shfl_down(acc.w, 20);
        acc.w += t1 + t2;
    }
    bool valid = lane < 10;
    float4 v4 = {-INFINITY, -INFINITY, -INFINITY, -INFINITY};
    if (valid) {
        float4 bv = *reinterpret_cast<const float4*>(&b2[lane * 4]);
        v4.x = acc.x + bv.x;
        v4.y = acc.y + bv.y;
        v4.z = acc.z + bv.z;
        v4.w = acc.w + bv.w;
    }
    float m = fmaxf(fmaxf(v4.x, v4.y), fmaxf(v4.z, v4.w));
#pragma unroll
    for (int off = 1; off < 16; off <<= 1) m = fmaxf(m, __shfl_xor(m, off));
    float ex = valid ? expf(v4.x - m) + expf(v4.y - m) + expf(v4.z - m) + expf(v4.w - m) : 0.f;
#pragma unroll
    for (int off = 1; off < 16; off <<= 1) ex += __shfl_xor(ex, off);
    float lse = m + logf(ex);
    if (valid) {
        float4 o;
        o.x = v4.x - lse;
        o.y = v4.y - lse;
        o.z = v4.z - lse;
        o.w = v4.w - lse;
        *reinterpret_cast<float4*>(&out[r * D2 + lane * 4]) = o;
    }
}

// ---------------------------------------------------------------------------
extern "C" void kernel_launch(void* const* d_in, const int* in_sizes, int n_in,
                              void* d_out, int out_size, void* d_ws, size_t ws_size,
                              hipStream_t stream) {
    const float* x = (const float*)d_in[0];
    const unsigned int* ei = (const unsigned int*)d_in[1];
    const float* ew = (const float*)d_in[2];
    const float* W1 = (const float*)d_in[3];
    const float* b1 = (const float*)d_in[4];
    const float* W2 = (const float*)d_in[5];
    const float* b2 = (const float*)d_in[6];
    float* out = (float*)d_out;

    char* w = (char*)d_ws;
    __half* Ah = (__half*)w;                                // 12.8 MB  fp16 x@W1
    float* B = (float*)(w + 12800000);                      // 25.6 MB  spmm1 out
    uint2* tmp8 = (uint2*)(w + 12800000);                   //   union with B (dead before spmm1)
    float* G = (float*)(w + 38400000);                      // 9.6 MB   [N][48] f32
    uint2* colwS = (uint2*)(w + 48000000);                  // 12.8 MB
    int* rowptr = (int*)(w + 60800000);                     // (N+1)*4
    int* bbase = (int*)(w + 61000832);                      // (NB+1)*4
    unsigned int* bcurp = (unsigned int*)(w + 61002432);    // NB*64
    unsigned int* gbhp = (unsigned int*)(w + 61027456);     // NB*64
    int* flag = (int*)(w + 61052480);                       // 4
    unsigned short* wh1 = (unsigned short*)(w + 61052544);  // 32 KB
    unsigned short* wl1 = (unsigned short*)(w + 61085312);  // 32 KB
    unsigned short* wh2 = (unsigned short*)(w + 61118080);  // 12 KB
    unsigned short* wl2 = (unsigned short*)(w + 61130368);  // 12 KB

    setup_k<<<114, 256, 0, stream>>>(ei, flag, gbhp, W1, wh1, wl1, W2, wh2, wl2);
    bhist_k<<<256, 256, 0, stream>>>(ei, flag, gbhp);
    bscan_k<<<1, 512, 0, stream>>>(gbhp, bbase, bcurp);
    bin_k<<<256, 256, 0, stream>>>(ei, ew, flag, bcurp, tmp8);
    csr_k<<<NB, 256, 0, stream>>>(tmp8, bbase, rowptr, colwS);

    gemm1_k<<<782, 256, 0, stream>>>(x, wh1, wl1, Ah);
    spmm1_k<<<N_NODES / 4, 256, 0, stream>>>(Ah, rowptr, colwS, B);
    gemm2_k<<<782, 256, 0, stream>>>(B, b1, wh2, wl2, G);
    spmm2lsm_k<<<N_NODES / 4, 256, 0, stream>>>(G, rowptr, colwS, b2, out);
}

// Round 7
// 276.382 us; speedup vs baseline: 1.4964x; 1.0052x over previous
//
#include <hip/hip_runtime.h>
#include <hip/hip_fp16.h>
#include <math.h>

#define N_NODES 50000
#define N_EDGES 1600000
#define D1 128
#define D2 40
#define D2P 64                    // padded G row (fp16) = 128 B = exactly 1 cache line
#define BROWS 128                 // rows per bucket
#define NB 391                    // ceil(N_NODES/BROWS)
#define CHUNK 6250                // N_EDGES / 256 (exact)

typedef __attribute__((ext_vector_type(8))) short bf16x8;
typedef __attribute__((ext_vector_type(4))) float f32x4;

// split f32 -> bf16 hi + bf16 lo (RNE both); x ~= hi + lo with ~2^-16 rel err
__device__ __forceinline__ void bf16_split(float v, unsigned short& h, unsigned short& l) {
    unsigned u = __float_as_uint(v);
    unsigned r = u + 0x7fffu + ((u >> 16) & 1u);
    h = (unsigned short)(r >> 16);
    float hf = __uint_as_float((unsigned)h << 16);
    float lof = v - hf;
    unsigned u2 = __float_as_uint(lof);
    unsigned r2 = u2 + 0x7fffu + ((u2 >> 16) & 1u);
    l = (unsigned short)(r2 >> 16);
}

// per-block int64-layout detect (values < 2^31 => odd 32b words all zero).
// ~8 KB of L2-hot reads per block; removes the cross-kernel flag dependency.
__device__ __forceinline__ int detect_is64_block(const unsigned int* ei) {
    __shared__ int any;
    if (threadIdx.x == 0) any = 0;
    __syncthreads();
    int a = 0;
    for (int i = threadIdx.x; i < 2048; i += 256) a |= (ei[2 * i + 1] != 0u);
    if (a) any = 1;
    __syncthreads();
    return any ? 0 : 1;  // 1 == int64 layout
}

__device__ __forceinline__ int edge_row(const unsigned int* ei, int e, int is64) {
    return (int)(is64 ? ei[2 * e] : ei[e]);
}
__device__ __forceinline__ int edge_col(const unsigned int* ei, int e, int is64) {
    return (int)(is64 ? ei[2 * (N_EDGES + e)] : ei[N_EDGES + e]);
}

// ---------------------------------------------------------------------------
// prep: b0..63 pack W1; b64..95 pack W2 (padded to 64 cols); b96..351 bhist.
__global__ __launch_bounds__(256) void prep_k(const unsigned int* __restrict__ ei,
                                              unsigned int* __restrict__ gbhp,
                                              const float* __restrict__ W1,
                                              unsigned short* __restrict__ wh1,
                                              unsigned short* __restrict__ wl1,
                                              const float* __restrict__ W2,
                                              unsigned short* __restrict__ wh2,
                                              unsigned short* __restrict__ wl2) {
    int b = blockIdx.x, t = threadIdx.x;
    if (b < 64) {
        int idx = b * 256 + t;  // 16384
        int k = idx >> 7, n = idx & 127;
        unsigned short h, l;
        bf16_split(W1[k * 128 + n], h, l);
        int nt = n >> 4, ks = k >> 5;
        int lane = (n & 15) | (((k >> 3) & 3) << 4);
        int j = k & 7;
        int dst = ((nt * 4 + ks) * 64 + lane) * 8 + j;
        wh1[dst] = h;
        wl1[dst] = l;
    } else if (b < 96) {
        int idx = (b - 64) * 256 + t;  // 8192
        int k = idx >> 6, n = idx & 63;
        float v = (n < D2) ? W2[k * D2 + n] : 0.f;
        unsigned short h, l;
        bf16_split(v, h, l);
        int nt = n >> 4, ks = k >> 5;
        int lane = (n & 15) | (((k >> 3) & 3) << 4);
        int j = k & 7;
        int dst = ((nt * 4 + ks) * 64 + lane) * 8 + j;
        wh2[dst] = h;
        wl2[dst] = l;
    } else {
        int is64 = detect_is64_block(ei);
        __shared__ unsigned int bh[NB];
        for (int i = t; i < NB; i += 256) bh[i] = 0;
        __syncthreads();
        int e0 = (b - 96) * CHUNK, e1 = e0 + CHUNK;
        for (int e = e0 + t; e < e1; e += 256) {
            atomicAdd(&bh[edge_row(ei, e, is64) >> 7], 1u);
        }
        __syncthreads();
        for (int i = t; i < NB; i += 256) {
            if (bh[i]) atomicAdd(&gbhp[i * 16], bh[i]);
        }
    }
}

__global__ __launch_bounds__(512) void bscan_k(const unsigned int* __restrict__ gbhp,
                                               int* __restrict__ bbase,
                                               unsigned int* __restrict__ bcurp) {
    __shared__ unsigned int s[512];
    int t = threadIdx.x;
    unsigned int v = (t < NB) ? gbhp[t * 16] : 0u;
    s[t] = v;
    __syncthreads();
    for (int off = 1; off < 512; off <<= 1) {
        unsigned int add = (t >= off) ? s[t - off] : 0u;
        __syncthreads();
        s[t] += add;
        __syncthreads();
    }
    if (t < NB) {
        unsigned int excl = s[t] - v;
        bbase[t] = (int)excl;
        bcurp[t * 16] = excl;
    }
    if (t == NB - 1) bbase[NB] = (int)s[t];
}

// ---------------------------------------------------------------------------
// work1: b0..255 = bin (edge binning into bucket regions);
//        b256..1037 = gemm1 (A(fp16) = x @ W1, MFMA split-bf16 3-pass).
// Independent work merged so gemm1's MFMA compute overlaps bin's memory phase.
__global__ __launch_bounds__(256) void work1_k(const unsigned int* __restrict__ ei,
                                               const float* __restrict__ ew,
                                               unsigned int* __restrict__ bcurp,
                                               uint2* __restrict__ tmp8,
                                               const float* __restrict__ x,
                                               const unsigned short* __restrict__ wh,
                                               const unsigned short* __restrict__ wl,
                                               __half* __restrict__ Ah) {
    int b = blockIdx.x, t = threadIdx.x;
    if (b < 256) {
        int is64 = detect_is64_block(ei);
        __shared__ unsigned int lh[NB];
        __shared__ unsigned int lcur[NB];
        for (int i = t; i < NB; i += 256) lh[i] = 0;
        __syncthreads();
        int e0 = b * CHUNK, e1 = e0 + CHUNK;
        for (int e = e0 + t; e < e1; e += 256) {
            atomicAdd(&lh[edge_row(ei, e, is64) >> 7], 1u);
        }
        __syncthreads();
        for (int i = t; i < NB; i += 256) {
            if (lh[i]) lcur[i] = atomicAdd(&bcurp[i * 16], lh[i]);
        }
        __syncthreads();
        for (int e = e0 + t; e < e1; e += 256) {
            int r = edge_row(ei, e, is64);
            int c = edge_col(ei, e, is64);
            int bk = r >> 7;
            unsigned int p = atomicAdd(&lcur[bk], 1u);
            uint2 rec;
            rec.x = ((unsigned int)(r & 127) << 24) | (unsigned int)c;
            rec.y = __float_as_uint(ew[e]);
            tmp8[p] = rec;
        }
    } else {
        int gb = b - 256;
        int w = t >> 6, l = t & 63;
        int row0 = gb * 64 + w * 16;
        int arow = row0 + (l & 15);
        if (arow > N_NODES - 1) arow = N_NODES - 1;
        int kbase = (l >> 4) * 8;
        bf16x8 ah[4], al[4];
#pragma unroll
        for (int ks = 0; ks < 4; ++ks) {
            const float* px = &x[arow * D1 + ks * 32 + kbase];
            float4 v0 = *reinterpret_cast<const float4*>(px);
            float4 v1 = *reinterpret_cast<const float4*>(px + 4);
            float vv[8] = {v0.x, v0.y, v0.z, v0.w, v1.x, v1.y, v1.z, v1.w};
#pragma unroll
            for (int j = 0; j < 8; ++j) {
                unsigned short h, lo2;
                bf16_split(vv[j], h, lo2);
                ah[ks][j] = (short)h;
                al[ks][j] = (short)lo2;
            }
        }
        f32x4 acc[8];
#pragma unroll
        for (int nt = 0; nt < 8; ++nt) acc[nt] = (f32x4)(0.f);
#pragma unroll
        for (int nt = 0; nt < 8; ++nt) {
#pragma unroll
            for (int ks = 0; ks < 4; ++ks) {
                int fo = ((nt * 4 + ks) * 64 + l) * 8;
                bf16x8 bh = *reinterpret_cast<const bf16x8*>(&wh[fo]);
                bf16x8 bl = *reinterpret_cast<const bf16x8*>(&wl[fo]);
                acc[nt] = __builtin_amdgcn_mfma_f32_16x16x32_bf16(ah[ks], bh, acc[nt], 0, 0, 0);
                acc[nt] = __builtin_amdgcn_mfma_f32_16x16x32_bf16(ah[ks], bl, acc[nt], 0, 0, 0);
                acc[nt] = __builtin_amdgcn_mfma_f32_16x16x32_bf16(al[ks], bh, acc[nt], 0, 0, 0);
            }
        }
        int crow0 = row0 + (l >> 4) * 4;
        int ccol = l & 15;
#pragma unroll
        for (int nt = 0; nt < 8; ++nt) {
#pragma unroll
            for (int r = 0; r < 4; ++r) {
                int rr = crow0 + r;
                if (rr < N_NODES) Ah[rr * D1 + nt * 16 + ccol] = __float2half_rn(acc[nt][r]);
            }
        }
    }
}

// Phase 2: per-bucket row counts -> rowptr, then in-window counting-sort scatter.
__global__ __launch_bounds__(256) void csr_k(const uint2* __restrict__ tmp8,
                                             const int* __restrict__ bbase,
                                             int* __restrict__ rowptr,
                                             uint2* __restrict__ colwS) {
    __shared__ unsigned int rcnt[BROWS];
    __shared__ unsigned int loff[BROWS];
    __shared__ unsigned int lcur[BROWS];
    int b = blockIdx.x;
    int t = threadIdx.x;
    int lo = bbase[b], hi = bbase[b + 1];
    int r0 = b * BROWS;
    int nrows = N_NODES - r0;
    if (nrows > BROWS) nrows = BROWS;
    if (t < BROWS) rcnt[t] = 0;
    __syncthreads();
    for (int j = lo + t; j < hi; j += 256) {
        atomicAdd(&rcnt[tmp8[j].x >> 24], 1u);
    }
    __syncthreads();
    if (t < BROWS) loff[t] = rcnt[t];
    __syncthreads();
    for (int off = 1; off < BROWS; off <<= 1) {
        unsigned int add = (t >= off && t < BROWS) ? loff[t - off] : 0u;
        __syncthreads();
        if (t < BROWS) loff[t] += add;
        __syncthreads();
    }
    if (t < BROWS) {
        unsigned int excl = loff[t] - rcnt[t];
        if (t < nrows) rowptr[r0 + t] = lo + (int)excl;
        lcur[t] = (unsigned int)lo + excl;
    }
    if (b == NB - 1 && t == 0) rowptr[N_NODES] = hi;
    __syncthreads();
    for (int j = lo + t; j < hi; j += 256) {
        uint2 rec = tmp8[j];
        unsigned int rl = rec.x >> 24;
        unsigned int p = atomicAdd(&lcur[rl], 1u);
        uint2 cw;
        cw.x = rec.x & 0xFFFFu;
        cw.y = rec.y;
        colwS[p] = cw;
    }
}

// ---------------------------------------------------------------------------
// B[r] = sum_j w_j * A[col_j]  — one row/wave, half-wave per edge.
// fp16 rows: 256 B = 4 cache lines per edge (line count is the MSHR-bound cost).
__global__ __launch_bounds__(256) void spmm1_k(const __half* __restrict__ Ah,
                                               const int* __restrict__ rowptr,
                                               const uint2* __restrict__ colwS,
                                               float* __restrict__ B) {
    int t = threadIdx.x;
    int r = blockIdx.x * 4 + (t >> 6);
    int lane = t & 63;
    int half = lane >> 5;
    int cg = lane & 31;
    int s = rowptr[r], e = rowptr[r + 1];
    float4 acc = {0.f, 0.f, 0.f, 0.f};
#pragma unroll 4
    for (int j = s + half; j < e; j += 2) {
        uint2 cw = colwS[j];
        float w = __uint_as_float(cw.y);
        uint2 q = *reinterpret_cast<const uint2*>(&Ah[cw.x * D1 + cg * 4]);
        float2 f0 = __half22float2(*reinterpret_cast<const __half2*>(&q.x));
        float2 f1 = __half22float2(*reinterpret_cast<const __half2*>(&q.y));
        acc.x += w * f0.x;
        acc.y += w * f0.y;
        acc.z += w * f1.x;
        acc.w += w * f1.y;
    }
    acc.x += __shfl_xor(acc.x, 32);
    acc.y += __shfl_xor(acc.y, 32);
    acc.z += __shfl_xor(acc.z, 32);
    acc.w += __shfl_xor(acc.w, 32);
    if (half == 0) *reinterpret_cast<float4*>(&B[r * D1 + cg * 4]) = acc;
}

// G(fp16 [N][64], 1 line/row) = relu(B + b1) @ W2  via MFMA split-bf16, 4 n-tiles.
__global__ __launch_bounds__(256) void gemm2_k(const float* __restrict__ Bm,
                                               const float* __restrict__ b1,
                                               const unsigned short* __restrict__ wh,
                                               const unsigned short* __restrict__ wl,
                                               __half* __restrict__ Gh) {
    int t = threadIdx.x;
    int w = t >> 6, l = t & 63;
    int row0 = blockIdx.x * 64 + w * 16;
    int arow = row0 + (l & 15);
    if (arow > N_NODES - 1) arow = N_NODES - 1;
    int kbase = (l >> 4) * 8;
    bf16x8 ah[4], al[4];
#pragma unroll
    for (int ks = 0; ks < 4; ++ks) {
        const float* pb = &Bm[arow * D1 + ks * 32 + kbase];
        const float* pb1 = &b1[ks * 32 + kbase];
        float4 v0 = *reinterpret_cast<const float4*>(pb);
        float4 v1 = *reinterpret_cast<const float4*>(pb + 4);
        float4 c0 = *reinterpret_cast<const float4*>(pb1);
        float4 c1 = *reinterpret_cast<const float4*>(pb1 + 4);
        float vv[8] = {v0.x + c0.x, v0.y + c0.y, v0.z + c0.z, v0.w + c0.w,
                       v1.x + c1.x, v1.y + c1.y, v1.z + c1.z, v1.w + c1.w};
#pragma unroll
        for (int j = 0; j < 8; ++j) {
            float rv = vv[j] > 0.f ? vv[j] : 0.f;
            unsigned short h, lo2;
            bf16_split(rv, h, lo2);
            ah[ks][j] = (short)h;
            al[ks][j] = (short)lo2;
        }
    }
    f32x4 acc[4];
#pragma unroll
    for (int nt = 0; nt < 4; ++nt) acc[nt] = (f32x4)(0.f);
#pragma unroll
    for (int nt = 0; nt < 4; ++nt) {
#pragma unroll
        for (int ks = 0; ks < 4; ++ks) {
            int fo = ((nt * 4 + ks) * 64 + l) * 8;
            bf16x8 bh = *reinterpret_cast<const bf16x8*>(&wh[fo]);
            bf16x8 bl = *reinterpret_cast<const bf16x8*>(&wl[fo]);
            acc[nt] = __builtin_amdgcn_mfma_f32_16x16x32_bf16(ah[ks], bh, acc[nt], 0, 0, 0);
            acc[nt] = __builtin_amdgcn_mfma_f32_16x16x32_bf16(ah[ks], bl, acc[nt], 0, 0, 0);
            acc[nt] = __builtin_amdgcn_mfma_f32_16x16x32_bf16(al[ks], bh, acc[nt], 0, 0, 0);
        }
    }
    int crow0 = row0 + (l >> 4) * 4;
    int ccol = l & 15;
#pragma unroll
    for (int nt = 0; nt < 4; ++nt) {
        int col = nt * 16 + ccol;
#pragma unroll
        for (int r = 0; r < 4; ++r) {
            int rr = crow0 + r;
            if (rr < N_NODES) Gh[rr * D2P + col] = __float2half_rn(acc[nt][r]);
        }
    }
}

// out[r] = log_softmax(sum_j w_j * G[col_j] + b2) — one wave/row.
// 4 slots x 16 lanes; each edge reads the full 128 B row = exactly 1 cache line.
__global__ __launch_bounds__(256) void spmm2lsm_k(const __half* __restrict__ Gh,
                                                  const int* __restrict__ rowptr,
                                                  const uint2* __restrict__ colwS,
                                                  const float* __restrict__ b2,
                                                  float* __restrict__ out) {
    int t = threadIdx.x;
    int r = blockIdx.x * 4 + (t >> 6);
    int lane = t & 63;
    int slot = lane >> 4;   // 0..3
    int li = lane & 15;     // col group: cols li*4..li*4+3 (fp16 x4 = 8 B)
    int s = rowptr[r], e = rowptr[r + 1];
    float4 acc = {0.f, 0.f, 0.f, 0.f};
#pragma unroll 2
    for (int j0 = s; j0 < e; j0 += 4) {
        uint2 cwv = colwS[min(j0 + (lane & 3), e - 1)];
        int j = j0 + slot;
        if (j < e) {
            unsigned cx = __shfl(cwv.x, slot);
            float wv = __uint_as_float(__shfl(cwv.y, slot));
            uint2 q = reinterpret_cast<const uint2*>(&Gh[cx * D2P])[li];
            float2 f0 = __half22float2(*reinterpret_cast<const __half2*>(&q.x));
            float2 f1 = __half22float2(*reinterpret_cast<const __half2*>(&q.y));
            acc.x += wv * f0.x;
            acc.y += wv * f0.y;
            acc.z += wv * f1.x;
            acc.w += wv * f1.y;
        }
    }
    // slot reduce: lanes 0..15 <- sum of 4 slots
    acc.x += __shfl_down(acc.x, 32);
    acc.y += __shfl_down(acc.y, 32);
    acc.z += __shfl_down(acc.z, 32);
    acc.w += __shfl_down(acc.w, 32);
    acc.x += __shfl_down(acc.x, 16);
    acc.y += __shfl_down(acc.y, 16);
    acc.z += __shfl_down(acc.z, 16);
    acc.w += __shfl_down(acc.w, 16);
    bool valid = (lane < 16) && (li < 10);
    float4 v4 = {-INFINITY, -INFINITY, -INFINITY, -INFINITY};
    if (valid) {
        float4 bv = *reinterpret_cast<const float4*>(&b2[li * 4]);
        v4.x = acc.x + bv.x;
        v4.y = acc.y + bv.y;
        v4.z = acc.z + bv.z;
        v4.w = acc.w + bv.w;
    }
    float m = fmaxf(fmaxf(v4.x, v4.y), fmaxf(v4.z, v4.w));
#pragma unroll
    for (int off = 1; off < 16; off <<= 1) m = fmaxf(m, __shfl_xor(m, off));
    float ex = valid ? expf(v4.x - m) + expf(v4.y - m) + expf(v4.z - m) + expf(v4.w - m) : 0.f;
#pragma unroll
    for (int off = 1; off < 16; off <<= 1) ex += __shfl_xor(ex, off);
    float lse = m + logf(ex);
    if (valid) {
        float4 o;
        o.x = v4.x - lse;
        o.y = v4.y - lse;
        o.z = v4.z - lse;
        o.w = v4.w - lse;
        *reinterpret_cast<float4*>(&out[r * D2 + li * 4]) = o;
    }
}

// ---------------------------------------------------------------------------
extern "C" void kernel_launch(void* const* d_in, const int* in_sizes, int n_in,
                              void* d_out, int out_size, void* d_ws, size_t ws_size,
                              hipStream_t stream) {
    const float* x = (const float*)d_in[0];
    const unsigned int* ei = (const unsigned int*)d_in[1];
    const float* ew = (const float*)d_in[2];
    const float* W1 = (const float*)d_in[3];
    const float* b1 = (const float*)d_in[4];
    const float* W2 = (const float*)d_in[5];
    const float* b2 = (const float*)d_in[6];
    float* out = (float*)d_out;

    char* w = (char*)d_ws;
    __half* Ah = (__half*)w;                                // 12.8 MB  fp16 x@W1
    float* B = (float*)(w + 12800000);                      // 25.6 MB  spmm1 out
    uint2* tmp8 = (uint2*)(w + 12800000);                   //   union with B (dead before spmm1)
    __half* Gh = (__half*)(w + 38400000);                   // 6.4 MB   fp16 [N][64]
    uint2* colwS = (uint2*)(w + 44800000);                  // 12.8 MB
    int* rowptr = (int*)(w + 57600000);                     // (N+1)*4
    int* bbase = (int*)(w + 57800064);                      // (NB+1)*4
    unsigned int* bcurp = (unsigned int*)(w + 57801664);    // NB*64
    unsigned int* gbhp = (unsigned int*)(w + 57826688);     // NB*64
    unsigned short* wh1 = (unsigned short*)(w + 57851712);  // 32 KB
    unsigned short* wl1 = (unsigned short*)(w + 57884480);  // 32 KB
    unsigned short* wh2 = (unsigned short*)(w + 57917248);  // 16 KB
    unsigned short* wl2 = (unsigned short*)(w + 57933632);  // 16 KB

    hipMemsetAsync(gbhp, 0, NB * 64, stream);
    prep_k<<<352, 256, 0, stream>>>(ei, gbhp, W1, wh1, wl1, W2, wh2, wl2);
    bscan_k<<<1, 512, 0, stream>>>(gbhp, bbase, bcurp);
    work1_k<<<1038, 256, 0, stream>>>(ei, ew, bcurp, tmp8, x, wh1, wl1, Ah);
    csr_k<<<NB, 256, 0, stream>>>(tmp8, bbase, rowptr, colwS);

    spmm1_k<<<N_NODES / 4, 256, 0, stream>>>(Ah, rowptr, colwS, B);
    gemm2_k<<<782, 256, 0, stream>>>(B, b1, wh2, wl2, Gh);
    spmm2lsm_k<<<N_NODES / 4, 256, 0, stream>>>(Gh, rowptr, colwS, b2, out);
}

// Round 8
// 259.975 us; speedup vs baseline: 1.5909x; 1.0631x over previous
//
#include <hip/hip_runtime.h>
#include <hip/hip_fp16.h>
#include <math.h>

#define N_NODES 50000
#define N_EDGES 1600000
#define D1 128
#define D2 40
#define D2P 64                    // padded G row (fp16) = 128 B = exactly 1 cache line
#define BROWS 128                 // rows per bucket
#define NB 391                    // ceil(N_NODES/BROWS)
#define CHUNK 6250                // N_EDGES / 256 (exact)
#define CSR_CAP 7000              // LDS record capacity in csr_k (bucket avg 4096, +45 sigma)

typedef __attribute__((ext_vector_type(8))) short bf16x8;
typedef __attribute__((ext_vector_type(4))) float f32x4;

// split f32 -> bf16 hi + bf16 lo (RNE both); x ~= hi + lo with ~2^-16 rel err
__device__ __forceinline__ void bf16_split(float v, unsigned short& h, unsigned short& l) {
    unsigned u = __float_as_uint(v);
    unsigned r = u + 0x7fffu + ((u >> 16) & 1u);
    h = (unsigned short)(r >> 16);
    float hf = __uint_as_float((unsigned)h << 16);
    float lof = v - hf;
    unsigned u2 = __float_as_uint(lof);
    unsigned r2 = u2 + 0x7fffu + ((u2 >> 16) & 1u);
    l = (unsigned short)(r2 >> 16);
}

// per-block int64-layout detect (values < 2^31 => odd 32b words all zero).
__device__ __forceinline__ int detect_is64_block(const unsigned int* ei) {
    __shared__ int any;
    if (threadIdx.x == 0) any = 0;
    __syncthreads();
    int a = 0;
    for (int i = threadIdx.x; i < 2048; i += 256) a |= (ei[2 * i + 1] != 0u);
    if (a) any = 1;
    __syncthreads();
    return any ? 0 : 1;  // 1 == int64 layout
}

__device__ __forceinline__ int edge_row(const unsigned int* ei, int e, int is64) {
    return (int)(is64 ? ei[2 * e] : ei[e]);
}
__device__ __forceinline__ int edge_col(const unsigned int* ei, int e, int is64) {
    return (int)(is64 ? ei[2 * (N_EDGES + e)] : ei[N_EDGES + e]);
}

// ---------------------------------------------------------------------------
// prep: b0..63 pack W1; b64..95 pack W2 (padded to 64 cols).
__global__ __launch_bounds__(256) void prep_k(const float* __restrict__ W1,
                                              unsigned short* __restrict__ wh1,
                                              unsigned short* __restrict__ wl1,
                                              const float* __restrict__ W2,
                                              unsigned short* __restrict__ wh2,
                                              unsigned short* __restrict__ wl2) {
    int b = blockIdx.x, t = threadIdx.x;
    if (b < 64) {
        int idx = b * 256 + t;  // 16384
        int k = idx >> 7, n = idx & 127;
        unsigned short h, l;
        bf16_split(W1[k * 128 + n], h, l);
        int nt = n >> 4, ks = k >> 5;
        int lane = (n & 15) | (((k >> 3) & 3) << 4);
        int j = k & 7;
        int dst = ((nt * 4 + ks) * 64 + lane) * 8 + j;
        wh1[dst] = h;
        wl1[dst] = l;
    } else {
        int idx = (b - 64) * 256 + t;  // 8192
        int k = idx >> 6, n = idx & 63;
        float v = (n < D2) ? W2[k * D2 + n] : 0.f;
        unsigned short h, l;
        bf16_split(v, h, l);
        int nt = n >> 4, ks = k >> 5;
        int lane = (n & 15) | (((k >> 3) & 3) << 4);
        int j = k & 7;
        int dst = ((nt * 4 + ks) * 64 + lane) * 8 + j;
        wh2[dst] = h;
        wl2[dst] = l;
    }
}

// ---------------------------------------------------------------------------
// bin: per block, LDS counting-sort the 6250-edge chunk by bucket; write the
// sorted chunk CONTIGUOUSLY to tmp8[block*CHUNK ...] (fully coalesced), the
// per-bucket offsets to bofs[block][0..NB], and accumulate the global bucket
// histogram (replaces the old bhist pass). rec.x = (row<<16) | col.
__global__ __launch_bounds__(256) void bin_k(const unsigned int* __restrict__ ei,
                                             const float* __restrict__ ew,
                                             unsigned int* __restrict__ gbhp,
                                             uint2* __restrict__ tmp8,
                                             unsigned int* __restrict__ bofs) {
    __shared__ uint2 lrec[CHUNK];          // 50000 B
    __shared__ unsigned int lh[NB];
    __shared__ unsigned int lstart[NB + 1];
    __shared__ unsigned int lcur[NB];
    __shared__ unsigned int ssum[256];
    int b = blockIdx.x, t = threadIdx.x;
    int is64 = detect_is64_block(ei);
    for (int i = t; i < NB; i += 256) lh[i] = 0;
    __syncthreads();
    int e0 = b * CHUNK, e1 = e0 + CHUNK;
    for (int e = e0 + t; e < e1; e += 256) {
        atomicAdd(&lh[edge_row(ei, e, is64) >> 7], 1u);
    }
    __syncthreads();
    // global bucket hist accumulate (for bscan)
    for (int i = t; i < NB; i += 256) {
        if (lh[i]) atomicAdd(&gbhp[i * 16], lh[i]);
    }
    // exclusive scan of lh: thread t owns buckets 2t, 2t+1
    unsigned int lsum = 0;
    if (t < 196) {
        lsum = lh[2 * t];
        if (2 * t + 1 < NB) lsum += lh[2 * t + 1];
    }
    ssum[t] = lsum;
    __syncthreads();
    for (int off = 1; off < 256; off <<= 1) {
        unsigned int add = (t >= off) ? ssum[t - off] : 0u;
        __syncthreads();
        ssum[t] += add;
        __syncthreads();
    }
    unsigned int run = (t == 0) ? 0u : ssum[t - 1];
    if (t < 196) {
        lstart[2 * t] = run;
        if (2 * t + 1 < NB) lstart[2 * t + 1] = run + lh[2 * t];
    }
    if (t == 0) lstart[NB] = CHUNK;
    __syncthreads();
    for (int i = t; i < NB; i += 256) lcur[i] = lstart[i];
    __syncthreads();
    // scatter into LDS (second pass over chunk; L2-hot)
    for (int e = e0 + t; e < e1; e += 256) {
        int r = edge_row(ei, e, is64);
        int c = edge_col(ei, e, is64);
        unsigned int p = atomicAdd(&lcur[r >> 7], 1u);
        uint2 rec;
        rec.x = ((unsigned int)r << 16) | (unsigned int)c;
        rec.y = __float_as_uint(ew[e]);
        lrec[p] = rec;
    }
    __syncthreads();
    // write bofs + sorted chunk (coalesced)
    for (int i = t; i <= NB; i += 256) bofs[b * (NB + 1) + i] = lstart[i];
    for (int p = t; p < CHUNK; p += 256) tmp8[e0 + p] = lrec[p];
}

__global__ __launch_bounds__(512) void bscan_k(const unsigned int* __restrict__ gbhp,
                                               int* __restrict__ bbase) {
    __shared__ unsigned int s[512];
    int t = threadIdx.x;
    unsigned int v = (t < NB) ? gbhp[t * 16] : 0u;
    s[t] = v;
    __syncthreads();
    for (int off = 1; off < 512; off <<= 1) {
        unsigned int add = (t >= off) ? s[t - off] : 0u;
        __syncthreads();
        s[t] += add;
        __syncthreads();
    }
    if (t < NB) bbase[t] = (int)(s[t] - v);
    if (t == NB - 1) bbase[NB] = (int)s[t];
}

// ---------------------------------------------------------------------------
// csr: one block per bucket. GATHER the bucket's runs from all 256 sorted
// chunks (random L3 reads — cheap), row-count -> rowptr, then in-window
// counting-sort scatter into colwS.
__global__ __launch_bounds__(256) void csr_k(const uint2* __restrict__ tmp8,
                                             const unsigned int* __restrict__ bofs,
                                             const int* __restrict__ bbase,
                                             int* __restrict__ rowptr,
                                             uint2* __restrict__ colwS) {
    __shared__ uint2 lrec[CSR_CAP];        // 56 KB
    __shared__ unsigned int ssum[256];
    __shared__ unsigned int rcnt[BROWS];
    __shared__ unsigned int loff[BROWS];
    __shared__ unsigned int lcur[BROWS];
    int b = blockIdx.x, t = threadIdx.x;
    // thread t == chunk t
    unsigned int mystart = bofs[t * (NB + 1) + b];
    unsigned int myend = bofs[t * (NB + 1) + b + 1];
    unsigned int mycnt = myend - mystart;
    ssum[t] = mycnt;
    __syncthreads();
    for (int off = 1; off < 256; off <<= 1) {
        unsigned int add = (t >= off) ? ssum[t - off] : 0u;
        __syncthreads();
        ssum[t] += add;
        __syncthreads();
    }
    unsigned int mybase = ssum[t] - mycnt;
    unsigned int total = ssum[255];
    // gather my run into LDS
    const uint2* src = &tmp8[t * CHUNK + mystart];
    for (unsigned int k = 0; k < mycnt; ++k) lrec[mybase + k] = src[k];
    if (t < BROWS) rcnt[t] = 0;
    __syncthreads();
    // per-row hist
    for (unsigned int p = t; p < total; p += 256) {
        atomicAdd(&rcnt[(lrec[p].x >> 16) & 127], 1u);
    }
    __syncthreads();
    if (t < BROWS) loff[t] = rcnt[t];
    __syncthreads();
    for (int off = 1; off < BROWS; off <<= 1) {
        unsigned int add = (t >= off && t < BROWS) ? loff[t - off] : 0u;
        __syncthreads();
        if (t < BROWS) loff[t] += add;
        __syncthreads();
    }
    int lo = bbase[b], hi = bbase[b + 1];
    int r0 = b * BROWS;
    int nrows = N_NODES - r0;
    if (nrows > BROWS) nrows = BROWS;
    if (t < BROWS) {
        unsigned int excl = loff[t] - rcnt[t];
        if (t < nrows) rowptr[r0 + t] = lo + (int)excl;
        lcur[t] = (unsigned int)lo + excl;
    }
    if (b == NB - 1 && t == 0) rowptr[N_NODES] = hi;
    __syncthreads();
    for (unsigned int p = t; p < total; p += 256) {
        uint2 rec = lrec[p];
        unsigned int rl = (rec.x >> 16) & 127;
        unsigned int pos = atomicAdd(&lcur[rl], 1u);
        uint2 cw;
        cw.x = rec.x & 0xFFFFu;
        cw.y = rec.y;
        colwS[pos] = cw;
    }
}

// ---------------------------------------------------------------------------
// A(fp16) = x @ W1 via mfma_f32_16x16x32_bf16, split-bf16 3-pass.
__global__ __launch_bounds__(256) void gemm1_k(const float* __restrict__ x,
                                               const unsigned short* __restrict__ wh,
                                               const unsigned short* __restrict__ wl,
                                               __half* __restrict__ Ah) {
    int t = threadIdx.x;
    int w = t >> 6, l = t & 63;
    int row0 = blockIdx.x * 64 + w * 16;
    int arow = row0 + (l & 15);
    if (arow > N_NODES - 1) arow = N_NODES - 1;
    int kbase = (l >> 4) * 8;
    bf16x8 ah[4], al[4];
#pragma unroll
    for (int ks = 0; ks < 4; ++ks) {
        const float* px = &x[arow * D1 + ks * 32 + kbase];
        float4 v0 = *reinterpret_cast<const float4*>(px);
        float4 v1 = *reinterpret_cast<const float4*>(px + 4);
        float vv[8] = {v0.x, v0.y, v0.z, v0.w, v1.x, v1.y, v1.z, v1.w};
#pragma unroll
        for (int j = 0; j < 8; ++j) {
            unsigned short h, lo2;
            bf16_split(vv[j], h, lo2);
            ah[ks][j] = (short)h;
            al[ks][j] = (short)lo2;
        }
    }
    f32x4 acc[8];
#pragma unroll
    for (int nt = 0; nt < 8; ++nt) acc[nt] = (f32x4)(0.f);
#pragma unroll
    for (int nt = 0; nt < 8; ++nt) {
#pragma unroll
        for (int ks = 0; ks < 4; ++ks) {
            int fo = ((nt * 4 + ks) * 64 + l) * 8;
            bf16x8 bh = *reinterpret_cast<const bf16x8*>(&wh[fo]);
            bf16x8 bl = *reinterpret_cast<const bf16x8*>(&wl[fo]);
            acc[nt] = __builtin_amdgcn_mfma_f32_16x16x32_bf16(ah[ks], bh, acc[nt], 0, 0, 0);
            acc[nt] = __builtin_amdgcn_mfma_f32_16x16x32_bf16(ah[ks], bl, acc[nt], 0, 0, 0);
            acc[nt] = __builtin_amdgcn_mfma_f32_16x16x32_bf16(al[ks], bh, acc[nt], 0, 0, 0);
        }
    }
    int crow0 = row0 + (l >> 4) * 4;
    int ccol = l & 15;
#pragma unroll
    for (int nt = 0; nt < 8; ++nt) {
#pragma unroll
        for (int r = 0; r < 4; ++r) {
            int rr = crow0 + r;
            if (rr < N_NODES) Ah[rr * D1 + nt * 16 + ccol] = __float2half_rn(acc[nt][r]);
        }
    }
}

// ---------------------------------------------------------------------------
// B(fp16)[r] = sum_j w_j * A[col_j] — one row/wave, half-wave per edge.
__global__ __launch_bounds__(256) void spmm1_k(const __half* __restrict__ Ah,
                                               const int* __restrict__ rowptr,
                                               const uint2* __restrict__ colwS,
                                               __half* __restrict__ Bh) {
    int t = threadIdx.x;
    int r = blockIdx.x * 4 + (t >> 6);
    int lane = t & 63;
    int half = lane >> 5;
    int cg = lane & 31;
    int s = rowptr[r], e = rowptr[r + 1];
    float4 acc = {0.f, 0.f, 0.f, 0.f};
#pragma unroll 4
    for (int j = s + half; j < e; j += 2) {
        uint2 cw = colwS[j];
        float w = __uint_as_float(cw.y);
        uint2 q = *reinterpret_cast<const uint2*>(&Ah[cw.x * D1 + cg * 4]);
        float2 f0 = __half22float2(*reinterpret_cast<const __half2*>(&q.x));
        float2 f1 = __half22float2(*reinterpret_cast<const __half2*>(&q.y));
        acc.x += w * f0.x;
        acc.y += w * f0.y;
        acc.z += w * f1.x;
        acc.w += w * f1.y;
    }
    acc.x += __shfl_xor(acc.x, 32);
    acc.y += __shfl_xor(acc.y, 32);
    acc.z += __shfl_xor(acc.z, 32);
    acc.w += __shfl_xor(acc.w, 32);
    if (half == 0) {
        unsigned p0 = ((unsigned)__half_as_ushort(__float2half_rn(acc.y)) << 16) |
                      __half_as_ushort(__float2half_rn(acc.x));
        unsigned p1 = ((unsigned)__half_as_ushort(__float2half_rn(acc.w)) << 16) |
                      __half_as_ushort(__float2half_rn(acc.z));
        uint2 st;
        st.x = p0;
        st.y = p1;
        *reinterpret_cast<uint2*>(&Bh[r * D1 + cg * 4]) = st;
    }
}

// G(fp16 [N][64]) = relu(B + b1) @ W2  via MFMA split-bf16, 4 n-tiles.
__global__ __launch_bounds__(256) void gemm2_k(const __half* __restrict__ Bh,
                                               const float* __restrict__ b1,
                                               const unsigned short* __restrict__ wh,
                                               const unsigned short* __restrict__ wl,
                                               __half* __restrict__ Gh) {
    int t = threadIdx.x;
    int w = t >> 6, l = t & 63;
    int row0 = blockIdx.x * 64 + w * 16;
    int arow = row0 + (l & 15);
    if (arow > N_NODES - 1) arow = N_NODES - 1;
    int kbase = (l >> 4) * 8;
    bf16x8 ah[4], al[4];
#pragma unroll
    for (int ks = 0; ks < 4; ++ks) {
        const __half* pb = &Bh[arow * D1 + ks * 32 + kbase];
        const float* pb1 = &b1[ks * 32 + kbase];
        uint4 q = *reinterpret_cast<const uint4*>(pb);
        float2 g0 = __half22float2(*reinterpret_cast<const __half2*>(&q.x));
        float2 g1 = __half22float2(*reinterpret_cast<const __half2*>(&q.y));
        float2 g2 = __half22float2(*reinterpret_cast<const __half2*>(&q.z));
        float2 g3 = __half22float2(*reinterpret_cast<const __half2*>(&q.w));
        float4 c0 = *reinterpret_cast<const float4*>(pb1);
        float4 c1 = *reinterpret_cast<const float4*>(pb1 + 4);
        float vv[8] = {g0.x + c0.x, g0.y + c0.y, g1.x + c0.z, g1.y + c0.w,
                       g2.x + c1.x, g2.y + c1.y, g3.x + c1.z, g3.y + c1.w};
#pragma unroll
        for (int j = 0; j < 8; ++j) {
            float rv = vv[j] > 0.f ? vv[j] : 0.f;
            unsigned short h, lo2;
            bf16_split(rv, h, lo2);
            ah[ks][j] = (short)h;
            al[ks][j] = (short)lo2;
        }
    }
    f32x4 acc[4];
#pragma unroll
    for (int nt = 0; nt < 4; ++nt) acc[nt] = (f32x4)(0.f);
#pragma unroll
    for (int nt = 0; nt < 4; ++nt) {
#pragma unroll
        for (int ks = 0; ks < 4; ++ks) {
            int fo = ((nt * 4 + ks) * 64 + l) * 8;
            bf16x8 bh = *reinterpret_cast<const bf16x8*>(&wh[fo]);
            bf16x8 bl = *reinterpret_cast<const bf16x8*>(&wl[fo]);
            acc[nt] = __builtin_amdgcn_mfma_f32_16x16x32_bf16(ah[ks], bh, acc[nt], 0, 0, 0);
            acc[nt] = __builtin_amdgcn_mfma_f32_16x16x32_bf16(ah[ks], bl, acc[nt], 0, 0, 0);
            acc[nt] = __builtin_amdgcn_mfma_f32_16x16x32_bf16(al[ks], bh, acc[nt], 0, 0, 0);
        }
    }
    int crow0 = row0 + (l >> 4) * 4;
    int ccol = l & 15;
#pragma unroll
    for (int nt = 0; nt < 4; ++nt) {
        int col = nt * 16 + ccol;
#pragma unroll
        for (int r = 0; r < 4; ++r) {
            int rr = crow0 + r;
            if (rr < N_NODES) Gh[rr * D2P + col] = __float2half_rn(acc[nt][r]);
        }
    }
}

// out[r] = log_softmax(sum_j w_j * G[col_j] + b2) — spmm1's proven structure:
// one row/wave, half-wave per edge, lane = col pair (4 B = 2 fp16);
// 32 lanes x 4 B = the full 128 B row = exactly 1 cache line per edge.
__global__ __launch_bounds__(256) void spmm2lsm_k(const __half* __restrict__ Gh,
                                                  const int* __restrict__ rowptr,
                                                  const uint2* __restrict__ colwS,
                                                  const float* __restrict__ b2,
                                                  float* __restrict__ out) {
    int t = threadIdx.x;
    int r = blockIdx.x * 4 + (t >> 6);
    int lane = t & 63;
    int half = lane >> 5;
    int cg = lane & 31;
    int s = rowptr[r], e = rowptr[r + 1];
    float2 acc = {0.f, 0.f};
#pragma unroll 4
    for (int j = s + half; j < e; j += 2) {
        uint2 cw = colwS[j];
        float w = __uint_as_float(cw.y);
        unsigned q = *reinterpret_cast<const unsigned*>(&Gh[cw.x * D2P + cg * 2]);
        float2 f = __half22float2(*reinterpret_cast<const __half2*>(&q));
        acc.x += w * f.x;
        acc.y += w * f.y;
    }
    acc.x += __shfl_xor(acc.x, 32);
    acc.y += __shfl_xor(acc.y, 32);
    bool valid = lane < 20;  // cols cg*2, cg*2+1 < 40
    float2 v2 = {-INFINITY, -INFINITY};
    if (valid) {
        float2 bv = reinterpret_cast<const float2*>(b2)[cg];
        v2.x = acc.x + bv.x;
        v2.y = acc.y + bv.y;
    }
    float m = fmaxf(v2.x, v2.y);
#pragma unroll
    for (int off = 1; off < 32; off <<= 1) m = fmaxf(m, __shfl_xor(m, off));
    float ex = valid ? expf(v2.x - m) + expf(v2.y - m) : 0.f;
#pragma unroll
    for (int off = 1; off < 32; off <<= 1) ex += __shfl_xor(ex, off);
    float lse = m + logf(ex);
    if (valid) {
        float2 o;
        o.x = v2.x - lse;
        o.y = v2.y - lse;
        *reinterpret_cast<float2*>(&out[r * D2 + cg * 2]) = o;
    }
}

// ---------------------------------------------------------------------------
extern "C" void kernel_launch(void* const* d_in, const int* in_sizes, int n_in,
                              void* d_out, int out_size, void* d_ws, size_t ws_size,
                              hipStream_t stream) {
    const float* x = (const float*)d_in[0];
    const unsigned int* ei = (const unsigned int*)d_in[1];
    const float* ew = (const float*)d_in[2];
    const float* W1 = (const float*)d_in[3];
    const float* b1 = (const float*)d_in[4];
    const float* W2 = (const float*)d_in[5];
    const float* b2 = (const float*)d_in[6];
    float* out = (float*)d_out;

    char* w = (char*)d_ws;
    __half* Ah = (__half*)w;                                // 12.8 MB  fp16 x@W1
    __half* Bh = (__half*)(w + 12800000);                   // 12.8 MB  fp16 spmm1 out
    uint2* tmp8 = (uint2*)(w + 25600000);                   // 12.8 MB  chunk-sorted records
    __half* Gh = (__half*)(w + 38400000);                   // 6.4 MB   fp16 [N][64]
    uint2* colwS = (uint2*)(w + 44800000);                  // 12.8 MB  CSR {col,w}
    int* rowptr = (int*)(w + 57600000);                     // (N+1)*4
    int* bbase = (int*)(w + 57800064);                      // (NB+1)*4
    unsigned int* bofs = (unsigned int*)(w + 57801664);     // 256*(NB+1)*4 = 401408
    unsigned int* gbhp = (unsigned int*)(w + 58203072);     // NB*64
    unsigned short* wh1 = (unsigned short*)(w + 58228096);  // 32 KB
    unsigned short* wl1 = (unsigned short*)(w + 58260864);  // 32 KB
    unsigned short* wh2 = (unsigned short*)(w + 58293632);  // 16 KB
    unsigned short* wl2 = (unsigned short*)(w + 58310016);  // 16 KB

    hipMemsetAsync(gbhp, 0, NB * 64, stream);
    prep_k<<<96, 256, 0, stream>>>(W1, wh1, wl1, W2, wh2, wl2);
    bin_k<<<256, 256, 0, stream>>>(ei, ew, gbhp, tmp8, bofs);
    bscan_k<<<1, 512, 0, stream>>>(gbhp, bbase);
    gemm1_k<<<782, 256, 0, stream>>>(x, wh1, wl1, Ah);
    csr_k<<<NB, 256, 0, stream>>>(tmp8, bofs, bbase, rowptr, colwS);

    spmm1_k<<<N_NODES / 4, 256, 0, stream>>>(Ah, rowptr, colwS, Bh);
    gemm2_k<<<782, 256, 0, stream>>>(Bh, b1, wh2, wl2, Gh);
    spmm2lsm_k<<<N_NODES / 4, 256, 0, stream>>>(Gh, rowptr, colwS, b2, out);
}

// Round 9
// 253.764 us; speedup vs baseline: 1.6298x; 1.0245x over previous
//
#include <hip/hip_runtime.h>
#include <hip/hip_fp16.h>
#include <math.h>

#define N_NODES 50000
#define N_EDGES 1600000
#define D1 128
#define D2 40
#define D2P 64                    // padded G row (fp16) = 128 B = exactly 1 cache line
#define BROWS 128                 // rows per bucket
#define NB 391                    // ceil(N_NODES/BROWS)
#define CHUNK 6250                // N_EDGES / 256 (exact)
#define CSR_CAP 7000              // LDS record capacity in csr_k (bucket avg 4096)

typedef __attribute__((ext_vector_type(8))) short bf16x8;
typedef __attribute__((ext_vector_type(4))) float f32x4;

// split f32 -> bf16 hi + bf16 lo (RNE both); x ~= hi + lo with ~2^-16 rel err
__device__ __forceinline__ void bf16_split(float v, unsigned short& h, unsigned short& l) {
    unsigned u = __float_as_uint(v);
    unsigned r = u + 0x7fffu + ((u >> 16) & 1u);
    h = (unsigned short)(r >> 16);
    float hf = __uint_as_float((unsigned)h << 16);
    float lof = v - hf;
    unsigned u2 = __float_as_uint(lof);
    unsigned r2 = u2 + 0x7fffu + ((u2 >> 16) & 1u);
    l = (unsigned short)(r2 >> 16);
}

// per-block int64-layout detect (values < 2^31 => odd 32b words all zero).
__device__ __forceinline__ int detect_is64_block(const unsigned int* ei) {
    __shared__ int any;
    if (threadIdx.x == 0) any = 0;
    __syncthreads();
    int a = 0;
    for (int i = threadIdx.x; i < 2048; i += 256) a |= (ei[2 * i + 1] != 0u);
    if (a) any = 1;
    __syncthreads();
    return any ? 0 : 1;  // 1 == int64 layout
}

__device__ __forceinline__ int edge_row(const unsigned int* ei, int e, int is64) {
    return (int)(is64 ? ei[2 * e] : ei[e]);
}
__device__ __forceinline__ int edge_col(const unsigned int* ei, int e, int is64) {
    return (int)(is64 ? ei[2 * (N_EDGES + e)] : ei[N_EDGES + e]);
}

// ---------------------------------------------------------------------------
// prep: b0..63 pack W1; b64..95 pack W2 (padded to 64 cols); b96..120 zero gbhp.
__global__ __launch_bounds__(256) void prep_k(const float* __restrict__ W1,
                                              unsigned short* __restrict__ wh1,
                                              unsigned short* __restrict__ wl1,
                                              const float* __restrict__ W2,
                                              unsigned short* __restrict__ wh2,
                                              unsigned short* __restrict__ wl2,
                                              unsigned int* __restrict__ gbhp) {
    int b = blockIdx.x, t = threadIdx.x;
    if (b < 64) {
        int idx = b * 256 + t;  // 16384
        int k = idx >> 7, n = idx & 127;
        unsigned short h, l;
        bf16_split(W1[k * 128 + n], h, l);
        int nt = n >> 4, ks = k >> 5;
        int lane = (n & 15) | (((k >> 3) & 3) << 4);
        int j = k & 7;
        int dst = ((nt * 4 + ks) * 64 + lane) * 8 + j;
        wh1[dst] = h;
        wl1[dst] = l;
    } else if (b < 96) {
        int idx = (b - 64) * 256 + t;  // 8192
        int k = idx >> 6, n = idx & 63;
        float v = (n < D2) ? W2[k * D2 + n] : 0.f;
        unsigned short h, l;
        bf16_split(v, h, l);
        int nt = n >> 4, ks = k >> 5;
        int lane = (n & 15) | (((k >> 3) & 3) << 4);
        int j = k & 7;
        int dst = ((nt * 4 + ks) * 64 + lane) * 8 + j;
        wh2[dst] = h;
        wl2[dst] = l;
    } else {
        int idx = (b - 96) * 256 + t;
        if (idx < NB * 16) gbhp[idx] = 0u;
    }
}

// ---------------------------------------------------------------------------
// bin: per block, LDS counting-sort the 6250-edge chunk by bucket; write the
// sorted chunk CONTIGUOUSLY to tmp8[block*CHUNK ...], per-bucket offsets to
// bofs[block][0..NB], accumulate global bucket hist. rec.x = (row<<16) | col.
__global__ __launch_bounds__(256) void bin_k(const unsigned int* __restrict__ ei,
                                             const float* __restrict__ ew,
                                             unsigned int* __restrict__ gbhp,
                                             uint2* __restrict__ tmp8,
                                             unsigned int* __restrict__ bofs) {
    __shared__ uint2 lrec[CHUNK];          // 50000 B
    __shared__ unsigned int lh[NB];
    __shared__ unsigned int lstart[NB + 1];
    __shared__ unsigned int lcur[NB];
    __shared__ unsigned int ssum[256];
    int b = blockIdx.x, t = threadIdx.x;
    int is64 = detect_is64_block(ei);
    for (int i = t; i < NB; i += 256) lh[i] = 0;
    __syncthreads();
    int e0 = b * CHUNK, e1 = e0 + CHUNK;
    for (int e = e0 + t; e < e1; e += 256) {
        atomicAdd(&lh[edge_row(ei, e, is64) >> 7], 1u);
    }
    __syncthreads();
    for (int i = t; i < NB; i += 256) {
        if (lh[i]) atomicAdd(&gbhp[i * 16], lh[i]);
    }
    // exclusive scan of lh: thread t owns buckets 2t, 2t+1
    unsigned int lsum = 0;
    if (t < 196) {
        lsum = lh[2 * t];
        if (2 * t + 1 < NB) lsum += lh[2 * t + 1];
    }
    ssum[t] = lsum;
    __syncthreads();
    for (int off = 1; off < 256; off <<= 1) {
        unsigned int add = (t >= off) ? ssum[t - off] : 0u;
        __syncthreads();
        ssum[t] += add;
        __syncthreads();
    }
    unsigned int run = (t == 0) ? 0u : ssum[t - 1];
    if (t < 196) {
        lstart[2 * t] = run;
        if (2 * t + 1 < NB) lstart[2 * t + 1] = run + lh[2 * t];
    }
    if (t == 0) lstart[NB] = CHUNK;
    __syncthreads();
    for (int i = t; i < NB; i += 256) lcur[i] = lstart[i];
    __syncthreads();
    for (int e = e0 + t; e < e1; e += 256) {
        int r = edge_row(ei, e, is64);
        int c = edge_col(ei, e, is64);
        unsigned int p = atomicAdd(&lcur[r >> 7], 1u);
        uint2 rec;
        rec.x = ((unsigned int)r << 16) | (unsigned int)c;
        rec.y = __float_as_uint(ew[e]);
        lrec[p] = rec;
    }
    __syncthreads();
    for (int i = t; i <= NB; i += 256) bofs[b * (NB + 1) + i] = lstart[i];
    for (int p = t; p < CHUNK; p += 256) tmp8[e0 + p] = lrec[p];
}

// ---------------------------------------------------------------------------
// csr: one block per bucket. Computes its own bucket base via in-LDS scan of
// gbhp (replaces the bscan kernel), gathers the bucket's runs from all 256
// sorted chunks, row-counts -> rowptr, in-window counting-sort into colwS.
__global__ __launch_bounds__(256) void csr_k(const uint2* __restrict__ tmp8,
                                             const unsigned int* __restrict__ bofs,
                                             const unsigned int* __restrict__ gbhp,
                                             int* __restrict__ rowptr,
                                             uint2* __restrict__ colwS) {
    __shared__ uint2 lrec[CSR_CAP];        // 56 KB
    __shared__ unsigned int ssum[256];
    __shared__ unsigned int sv0[256];
    __shared__ unsigned int rcnt[BROWS];
    __shared__ unsigned int loff[BROWS];
    __shared__ unsigned int lcur[BROWS];
    __shared__ int s_lo, s_hi;
    int b = blockIdx.x, t = threadIdx.x;
    // --- bucket base: scan gbhp (2 buckets per thread) ---
    unsigned int v0 = (2 * t < NB) ? gbhp[(2 * t) * 16] : 0u;
    unsigned int v1 = (2 * t + 1 < NB) ? gbhp[(2 * t + 1) * 16] : 0u;
    sv0[t] = v0;
    ssum[t] = v0 + v1;
    __syncthreads();
    for (int off = 1; off < 256; off <<= 1) {
        unsigned int add = (t >= off) ? ssum[t - off] : 0u;
        __syncthreads();
        ssum[t] += add;
        __syncthreads();
    }
    if (t == 0) {
        int pi = b >> 1;
        unsigned int lo = (pi == 0) ? 0u : ssum[pi - 1];
        if (b & 1) lo += sv0[pi];
        unsigned int cntb = (b & 1) ? (ssum[pi] - ((pi == 0) ? 0u : ssum[pi - 1]) - sv0[pi])
                                    : sv0[pi];
        s_lo = (int)lo;
        s_hi = (int)(lo + cntb);
    }
    __syncthreads();
    int lo = s_lo, hi = s_hi;
    // --- gather my chunk-run (thread t == chunk t) ---
    unsigned int mystart = bofs[t * (NB + 1) + b];
    unsigned int myend = bofs[t * (NB + 1) + b + 1];
    unsigned int mycnt = myend - mystart;
    ssum[t] = mycnt;
    __syncthreads();
    for (int off = 1; off < 256; off <<= 1) {
        unsigned int add = (t >= off) ? ssum[t - off] : 0u;
        __syncthreads();
        ssum[t] += add;
        __syncthreads();
    }
    unsigned int mybase = ssum[t] - mycnt;
    unsigned int total = ssum[255];
    const uint2* src = &tmp8[t * CHUNK + mystart];
    for (unsigned int k = 0; k < mycnt; ++k) lrec[mybase + k] = src[k];
    if (t < BROWS) rcnt[t] = 0;
    __syncthreads();
    for (unsigned int p = t; p < total; p += 256) {
        atomicAdd(&rcnt[(lrec[p].x >> 16) & 127], 1u);
    }
    __syncthreads();
    if (t < BROWS) loff[t] = rcnt[t];
    __syncthreads();
    for (int off = 1; off < BROWS; off <<= 1) {
        unsigned int add = (t >= off && t < BROWS) ? loff[t - off] : 0u;
        __syncthreads();
        if (t < BROWS) loff[t] += add;
        __syncthreads();
    }
    int r0 = b * BROWS;
    int nrows = N_NODES - r0;
    if (nrows > BROWS) nrows = BROWS;
    if (t < BROWS) {
        unsigned int excl = loff[t] - rcnt[t];
        if (t < nrows) rowptr[r0 + t] = lo + (int)excl;
        lcur[t] = (unsigned int)lo + excl;
    }
    if (b == NB - 1 && t == 0) rowptr[N_NODES] = hi;
    __syncthreads();
    for (unsigned int p = t; p < total; p += 256) {
        uint2 rec = lrec[p];
        unsigned int rl = (rec.x >> 16) & 127;
        unsigned int pos = atomicAdd(&lcur[rl], 1u);
        uint2 cw;
        cw.x = rec.x & 0xFFFFu;
        cw.y = rec.y;
        colwS[pos] = cw;
    }
}

// ---------------------------------------------------------------------------
// A(fp16) = x @ W1 via mfma_f32_16x16x32_bf16, split-bf16 3-pass.
__global__ __launch_bounds__(256) void gemm1_k(const float* __restrict__ x,
                                               const unsigned short* __restrict__ wh,
                                               const unsigned short* __restrict__ wl,
                                               __half* __restrict__ Ah) {
    int t = threadIdx.x;
    int w = t >> 6, l = t & 63;
    int row0 = blockIdx.x * 64 + w * 16;
    int arow = row0 + (l & 15);
    if (arow > N_NODES - 1) arow = N_NODES - 1;
    int kbase = (l >> 4) * 8;
    bf16x8 ah[4], al[4];
#pragma unroll
    for (int ks = 0; ks < 4; ++ks) {
        const float* px = &x[arow * D1 + ks * 32 + kbase];
        float4 v0 = *reinterpret_cast<const float4*>(px);
        float4 v1 = *reinterpret_cast<const float4*>(px + 4);
        float vv[8] = {v0.x, v0.y, v0.z, v0.w, v1.x, v1.y, v1.z, v1.w};
#pragma unroll
        for (int j = 0; j < 8; ++j) {
            unsigned short h, lo2;
            bf16_split(vv[j], h, lo2);
            ah[ks][j] = (short)h;
            al[ks][j] = (short)lo2;
        }
    }
    f32x4 acc[8];
#pragma unroll
    for (int nt = 0; nt < 8; ++nt) acc[nt] = (f32x4)(0.f);
#pragma unroll
    for (int nt = 0; nt < 8; ++nt) {
#pragma unroll
        for (int ks = 0; ks < 4; ++ks) {
            int fo = ((nt * 4 + ks) * 64 + l) * 8;
            bf16x8 bh = *reinterpret_cast<const bf16x8*>(&wh[fo]);
            bf16x8 bl = *reinterpret_cast<const bf16x8*>(&wl[fo]);
            acc[nt] = __builtin_amdgcn_mfma_f32_16x16x32_bf16(ah[ks], bh, acc[nt], 0, 0, 0);
            acc[nt] = __builtin_amdgcn_mfma_f32_16x16x32_bf16(ah[ks], bl, acc[nt], 0, 0, 0);
            acc[nt] = __builtin_amdgcn_mfma_f32_16x16x32_bf16(al[ks], bh, acc[nt], 0, 0, 0);
        }
    }
    int crow0 = row0 + (l >> 4) * 4;
    int ccol = l & 15;
#pragma unroll
    for (int nt = 0; nt < 8; ++nt) {
#pragma unroll
        for (int r = 0; r < 4; ++r) {
            int rr = crow0 + r;
            if (rr < N_NODES) Ah[rr * D1 + nt * 16 + ccol] = __float2half_rn(acc[nt][r]);
        }
    }
}

// ---------------------------------------------------------------------------
// Fused spmm1 + gemm2:
//   h[r] = relu(sum_j w_j * A[col_j] + b1)   (gather phase, per wave, 4 rows)
//   G[16 rows] = h @ W2                      (MFMA epilogue, wave w = n-tile w)
// Block = 4 waves x 4 rows = 16 rows; h staged in LDS [16][132] (pad -> 2-way
// bank conflict = free). Kills the gemm2 kernel + the 25.6 MB B round-trip.
__global__ __launch_bounds__(256) void spmm1g_k(const __half* __restrict__ Ah,
                                                const int* __restrict__ rowptr,
                                                const uint2* __restrict__ colwS,
                                                const float* __restrict__ b1,
                                                const unsigned short* __restrict__ wh,
                                                const unsigned short* __restrict__ wl,
                                                __half* __restrict__ Gh) {
    __shared__ float hrow[16][132];
    int t = threadIdx.x;
    int w = t >> 6, lane = t & 63;
    int half = lane >> 5;
    int cg = lane & 31;
    int row0 = blockIdx.x * 16;
    float4 bv = *reinterpret_cast<const float4*>(&b1[cg * 4]);
#pragma unroll
    for (int i = 0; i < 4; ++i) {
        int r = row0 + w * 4 + i;
        int s = rowptr[r], e = rowptr[r + 1];
        float4 acc = {0.f, 0.f, 0.f, 0.f};
#pragma unroll 4
        for (int j = s + half; j < e; j += 2) {
            uint2 cw = colwS[j];
            float wv = __uint_as_float(cw.y);
            uint2 q = *reinterpret_cast<const uint2*>(&Ah[cw.x * D1 + cg * 4]);
            float2 f0 = __half22float2(*reinterpret_cast<const __half2*>(&q.x));
            float2 f1 = __half22float2(*reinterpret_cast<const __half2*>(&q.y));
            acc.x += wv * f0.x;
            acc.y += wv * f0.y;
            acc.z += wv * f1.x;
            acc.w += wv * f1.y;
        }
        acc.x += __shfl_xor(acc.x, 32);
        acc.y += __shfl_xor(acc.y, 32);
        acc.z += __shfl_xor(acc.z, 32);
        acc.w += __shfl_xor(acc.w, 32);
        if (half == 0) {
            float4 h;
            h.x = fmaxf(acc.x + bv.x, 0.f);
            h.y = fmaxf(acc.y + bv.y, 0.f);
            h.z = fmaxf(acc.z + bv.z, 0.f);
            h.w = fmaxf(acc.w + bv.w, 0.f);
            *reinterpret_cast<float4*>(&hrow[w * 4 + i][cg * 4]) = h;
        }
    }
    __syncthreads();
    // MFMA epilogue: wave w computes output n-tile w (cols w*16 .. w*16+15)
    int l = lane;
    int kb = (l >> 4) * 8;
    bf16x8 ah[4], al[4];
#pragma unroll
    for (int ks = 0; ks < 4; ++ks) {
        const float* ph = &hrow[l & 15][ks * 32 + kb];
        float4 v0 = *reinterpret_cast<const float4*>(ph);
        float4 v1 = *reinterpret_cast<const float4*>(ph + 4);
        float vv[8] = {v0.x, v0.y, v0.z, v0.w, v1.x, v1.y, v1.z, v1.w};
#pragma unroll
        for (int j = 0; j < 8; ++j) {
            unsigned short h, lo2;
            bf16_split(vv[j], h, lo2);
            ah[ks][j] = (short)h;
            al[ks][j] = (short)lo2;
        }
    }
    f32x4 acc2 = (f32x4)(0.f);
#pragma unroll
    for (int ks = 0; ks < 4; ++ks) {
        int fo = ((w * 4 + ks) * 64 + l) * 8;
        bf16x8 bh = *reinterpret_cast<const bf16x8*>(&wh[fo]);
        bf16x8 bl = *reinterpret_cast<const bf16x8*>(&wl[fo]);
        acc2 = __builtin_amdgcn_mfma_f32_16x16x32_bf16(ah[ks], bh, acc2, 0, 0, 0);
        acc2 = __builtin_amdgcn_mfma_f32_16x16x32_bf16(ah[ks], bl, acc2, 0, 0, 0);
        acc2 = __builtin_amdgcn_mfma_f32_16x16x32_bf16(al[ks], bh, acc2, 0, 0, 0);
    }
    int crow0 = row0 + (l >> 4) * 4;
    int ccol = w * 16 + (l & 15);
#pragma unroll
    for (int r = 0; r < 4; ++r) {
        Gh[(crow0 + r) * D2P + ccol] = __float2half_rn(acc2[r]);
    }
}

// out[r] = log_softmax(sum_j w_j * G[col_j] + b2) — one row/wave, half-wave
// per edge, 32 lanes x 4 B = the full 128 B row = exactly 1 cache line.
__global__ __launch_bounds__(256) void spmm2lsm_k(const __half* __restrict__ Gh,
                                                  const int* __restrict__ rowptr,
                                                  const uint2* __restrict__ colwS,
                                                  const float* __restrict__ b2,
                                                  float* __restrict__ out) {
    int t = threadIdx.x;
    int r = blockIdx.x * 4 + (t >> 6);
    int lane = t & 63;
    int half = lane >> 5;
    int cg = lane & 31;
    int s = rowptr[r], e = rowptr[r + 1];
    float2 acc = {0.f, 0.f};
#pragma unroll 4
    for (int j = s + half; j < e; j += 2) {
        uint2 cw = colwS[j];
        float w = __uint_as_float(cw.y);
        unsigned q = *reinterpret_cast<const unsigned*>(&Gh[cw.x * D2P + cg * 2]);
        float2 f = __half22float2(*reinterpret_cast<const __half2*>(&q));
        acc.x += w * f.x;
        acc.y += w * f.y;
    }
    acc.x += __shfl_xor(acc.x, 32);
    acc.y += __shfl_xor(acc.y, 32);
    bool valid = lane < 20;  // cols cg*2, cg*2+1 < 40
    float2 v2 = {-INFINITY, -INFINITY};
    if (valid) {
        float2 bv = reinterpret_cast<const float2*>(b2)[cg];
        v2.x = acc.x + bv.x;
        v2.y = acc.y + bv.y;
    }
    float m = fmaxf(v2.x, v2.y);
#pragma unroll
    for (int off = 1; off < 32; off <<= 1) m = fmaxf(m, __shfl_xor(m, off));
    float ex = valid ? expf(v2.x - m) + expf(v2.y - m) : 0.f;
#pragma unroll
    for (int off = 1; off < 32; off <<= 1) ex += __shfl_xor(ex, off);
    float lse = m + logf(ex);
    if (valid) {
        float2 o;
        o.x = v2.x - lse;
        o.y = v2.y - lse;
        *reinterpret_cast<float2*>(&out[r * D2 + cg * 2]) = o;
    }
}

// ---------------------------------------------------------------------------
extern "C" void kernel_launch(void* const* d_in, const int* in_sizes, int n_in,
                              void* d_out, int out_size, void* d_ws, size_t ws_size,
                              hipStream_t stream) {
    const float* x = (const float*)d_in[0];
    const unsigned int* ei = (const unsigned int*)d_in[1];
    const float* ew = (const float*)d_in[2];
    const float* W1 = (const float*)d_in[3];
    const float* b1 = (const float*)d_in[4];
    const float* W2 = (const float*)d_in[5];
    const float* b2 = (const float*)d_in[6];
    float* out = (float*)d_out;

    char* w = (char*)d_ws;
    __half* Ah = (__half*)w;                                // 12.8 MB  fp16 x@W1
    uint2* tmp8 = (uint2*)(w + 12800000);                   // 12.8 MB  chunk-sorted records
    __half* Gh = (__half*)(w + 25600000);                   // 6.4 MB   fp16 [N][64]
    uint2* colwS = (uint2*)(w + 32000000);                  // 12.8 MB  CSR {col,w}
    int* rowptr = (int*)(w + 44800000);                     // (N+1)*4
    unsigned int* bofs = (unsigned int*)(w + 45000064);     // 256*(NB+1)*4 = 401408
    unsigned int* gbhp = (unsigned int*)(w + 45401472);     // NB*64
    unsigned short* wh1 = (unsigned short*)(w + 45426496);  // 32 KB
    unsigned short* wl1 = (unsigned short*)(w + 45459264);  // 32 KB
    unsigned short* wh2 = (unsigned short*)(w + 45492032);  // 16 KB
    unsigned short* wl2 = (unsigned short*)(w + 45508416);  // 16 KB

    prep_k<<<121, 256, 0, stream>>>(W1, wh1, wl1, W2, wh2, wl2, gbhp);
    bin_k<<<256, 256, 0, stream>>>(ei, ew, gbhp, tmp8, bofs);
    gemm1_k<<<782, 256, 0, stream>>>(x, wh1, wl1, Ah);
    csr_k<<<NB, 256, 0, stream>>>(tmp8, bofs, gbhp, rowptr, colwS);

    spmm1g_k<<<N_NODES / 16, 256, 0, stream>>>(Ah, rowptr, colwS, b1, wh2, wl2, Gh);
    spmm2lsm_k<<<N_NODES / 4, 256, 0, stream>>>(Gh, rowptr, colwS, b2, out);
}

// Round 10
// 243.319 us; speedup vs baseline: 1.6998x; 1.0429x over previous
//
#include <hip/hip_runtime.h>
#include <hip/hip_fp16.h>
#include <math.h>

#define N_NODES 50000
#define N_EDGES 1600000
#define D1 128
#define D2 40
#define D2P 64                    // padded G row (fp16) = 128 B = exactly 1 cache line
#define BROWS 128                 // rows per bucket
#define NB 391                    // ceil(N_NODES/BROWS)
#define CHUNK 6250                // N_EDGES / 256 (exact)
#define CSR_CAP 7000              // LDS record capacity in csr_k (bucket avg 4096)

typedef __attribute__((ext_vector_type(8))) short bf16x8;
typedef __attribute__((ext_vector_type(4))) float f32x4;

// split f32 -> bf16 hi + bf16 lo (RNE both); x ~= hi + lo with ~2^-16 rel err
__device__ __forceinline__ void bf16_split(float v, unsigned short& h, unsigned short& l) {
    unsigned u = __float_as_uint(v);
    unsigned r = u + 0x7fffu + ((u >> 16) & 1u);
    h = (unsigned short)(r >> 16);
    float hf = __uint_as_float((unsigned)h << 16);
    float lof = v - hf;
    unsigned u2 = __float_as_uint(lof);
    unsigned r2 = u2 + 0x7fffu + ((u2 >> 16) & 1u);
    l = (unsigned short)(r2 >> 16);
}

// per-block int64-layout detect (values < 2^31 => odd 32b words all zero).
__device__ __forceinline__ int detect_is64_block(const unsigned int* ei) {
    __shared__ int any;
    if (threadIdx.x == 0) any = 0;
    __syncthreads();
    int a = 0;
    for (int i = threadIdx.x; i < 2048; i += 256) a |= (ei[2 * i + 1] != 0u);
    if (a) any = 1;
    __syncthreads();
    return any ? 0 : 1;  // 1 == int64 layout
}

__device__ __forceinline__ int edge_row(const unsigned int* ei, int e, int is64) {
    return (int)(is64 ? ei[2 * e] : ei[e]);
}
__device__ __forceinline__ int edge_col(const unsigned int* ei, int e, int is64) {
    return (int)(is64 ? ei[2 * (N_EDGES + e)] : ei[N_EDGES + e]);
}

// ---------------------------------------------------------------------------
// prep: b0..63 pack W1; b64..95 pack W2 (padded to 64 cols); b96..120 zero gbhp.
__global__ __launch_bounds__(256) void prep_k(const float* __restrict__ W1,
                                              unsigned short* __restrict__ wh1,
                                              unsigned short* __restrict__ wl1,
                                              const float* __restrict__ W2,
                                              unsigned short* __restrict__ wh2,
                                              unsigned short* __restrict__ wl2,
                                              unsigned int* __restrict__ gbhp) {
    int b = blockIdx.x, t = threadIdx.x;
    if (b < 64) {
        int idx = b * 256 + t;  // 16384
        int k = idx >> 7, n = idx & 127;
        unsigned short h, l;
        bf16_split(W1[k * 128 + n], h, l);
        int nt = n >> 4, ks = k >> 5;
        int lane = (n & 15) | (((k >> 3) & 3) << 4);
        int j = k & 7;
        int dst = ((nt * 4 + ks) * 64 + lane) * 8 + j;
        wh1[dst] = h;
        wl1[dst] = l;
    } else if (b < 96) {
        int idx = (b - 64) * 256 + t;  // 8192
        int k = idx >> 6, n = idx & 63;
        float v = (n < D2) ? W2[k * D2 + n] : 0.f;
        unsigned short h, l;
        bf16_split(v, h, l);
        int nt = n >> 4, ks = k >> 5;
        int lane = (n & 15) | (((k >> 3) & 3) << 4);
        int j = k & 7;
        int dst = ((nt * 4 + ks) * 64 + lane) * 8 + j;
        wh2[dst] = h;
        wl2[dst] = l;
    } else {
        int idx = (b - 96) * 256 + t;
        if (idx < NB * 16) gbhp[idx] = 0u;
    }
}

// ---------------------------------------------------------------------------
// bin: per block, LDS counting-sort the 6250-edge chunk by bucket; write the
// sorted chunk CONTIGUOUSLY to tmp8[block*CHUNK ...], per-bucket offsets to
// bofs[block][0..NB], accumulate global bucket hist. rec.x = (row<<16) | col.
__global__ __launch_bounds__(256) void bin_k(const unsigned int* __restrict__ ei,
                                             const float* __restrict__ ew,
                                             unsigned int* __restrict__ gbhp,
                                             uint2* __restrict__ tmp8,
                                             unsigned int* __restrict__ bofs) {
    __shared__ uint2 lrec[CHUNK];          // 50000 B
    __shared__ unsigned int lh[NB];
    __shared__ unsigned int lstart[NB + 1];
    __shared__ unsigned int lcur[NB];
    __shared__ unsigned int ssum[256];
    int b = blockIdx.x, t = threadIdx.x;
    int is64 = detect_is64_block(ei);
    for (int i = t; i < NB; i += 256) lh[i] = 0;
    __syncthreads();
    int e0 = b * CHUNK, e1 = e0 + CHUNK;
    for (int e = e0 + t; e < e1; e += 256) {
        atomicAdd(&lh[edge_row(ei, e, is64) >> 7], 1u);
    }
    __syncthreads();
    for (int i = t; i < NB; i += 256) {
        if (lh[i]) atomicAdd(&gbhp[i * 16], lh[i]);
    }
    // exclusive scan of lh: thread t owns buckets 2t, 2t+1
    unsigned int lsum = 0;
    if (t < 196) {
        lsum = lh[2 * t];
        if (2 * t + 1 < NB) lsum += lh[2 * t + 1];
    }
    ssum[t] = lsum;
    __syncthreads();
    for (int off = 1; off < 256; off <<= 1) {
        unsigned int add = (t >= off) ? ssum[t - off] : 0u;
        __syncthreads();
        ssum[t] += add;
        __syncthreads();
    }
    unsigned int run = (t == 0) ? 0u : ssum[t - 1];
    if (t < 196) {
        lstart[2 * t] = run;
        if (2 * t + 1 < NB) lstart[2 * t + 1] = run + lh[2 * t];
    }
    if (t == 0) lstart[NB] = CHUNK;
    __syncthreads();
    for (int i = t; i < NB; i += 256) lcur[i] = lstart[i];
    __syncthreads();
    for (int e = e0 + t; e < e1; e += 256) {
        int r = edge_row(ei, e, is64);
        int c = edge_col(ei, e, is64);
        unsigned int p = atomicAdd(&lcur[r >> 7], 1u);
        uint2 rec;
        rec.x = ((unsigned int)r << 16) | (unsigned int)c;
        rec.y = __float_as_uint(ew[e]);
        lrec[p] = rec;
    }
    __syncthreads();
    for (int i = t; i <= NB; i += 256) bofs[b * (NB + 1) + i] = lstart[i];
    for (int p = t; p < CHUNK; p += 256) tmp8[e0 + p] = lrec[p];
}

// ---------------------------------------------------------------------------
// csr: one block per bucket. Computes its own bucket base via in-LDS scan of
// gbhp, gathers the bucket's runs from all 256 sorted chunks, row-counts ->
// rowptr, in-window counting-sort into colwS.
__global__ __launch_bounds__(256) void csr_k(const uint2* __restrict__ tmp8,
                                             const unsigned int* __restrict__ bofs,
                                             const unsigned int* __restrict__ gbhp,
                                             int* __restrict__ rowptr,
                                             uint2* __restrict__ colwS) {
    __shared__ uint2 lrec[CSR_CAP];        // 56 KB
    __shared__ unsigned int ssum[256];
    __shared__ unsigned int sv0[256];
    __shared__ unsigned int rcnt[BROWS];
    __shared__ unsigned int loff[BROWS];
    __shared__ unsigned int lcur[BROWS];
    __shared__ int s_lo, s_hi;
    int b = blockIdx.x, t = threadIdx.x;
    // --- bucket base: scan gbhp (2 buckets per thread) ---
    unsigned int v0 = (2 * t < NB) ? gbhp[(2 * t) * 16] : 0u;
    unsigned int v1 = (2 * t + 1 < NB) ? gbhp[(2 * t + 1) * 16] : 0u;
    sv0[t] = v0;
    ssum[t] = v0 + v1;
    __syncthreads();
    for (int off = 1; off < 256; off <<= 1) {
        unsigned int add = (t >= off) ? ssum[t - off] : 0u;
        __syncthreads();
        ssum[t] += add;
        __syncthreads();
    }
    if (t == 0) {
        int pi = b >> 1;
        unsigned int lo = (pi == 0) ? 0u : ssum[pi - 1];
        if (b & 1) lo += sv0[pi];
        unsigned int cntb = (b & 1) ? (ssum[pi] - ((pi == 0) ? 0u : ssum[pi - 1]) - sv0[pi])
                                    : sv0[pi];
        s_lo = (int)lo;
        s_hi = (int)(lo + cntb);
    }
    __syncthreads();
    int lo = s_lo, hi = s_hi;
    // --- gather my chunk-run (thread t == chunk t) ---
    unsigned int mystart = bofs[t * (NB + 1) + b];
    unsigned int myend = bofs[t * (NB + 1) + b + 1];
    unsigned int mycnt = myend - mystart;
    ssum[t] = mycnt;
    __syncthreads();
    for (int off = 1; off < 256; off <<= 1) {
        unsigned int add = (t >= off) ? ssum[t - off] : 0u;
        __syncthreads();
        ssum[t] += add;
        __syncthreads();
    }
    unsigned int mybase = ssum[t] - mycnt;
    unsigned int total = ssum[255];
    const uint2* src = &tmp8[t * CHUNK + mystart];
    for (unsigned int k = 0; k < mycnt; ++k) lrec[mybase + k] = src[k];
    if (t < BROWS) rcnt[t] = 0;
    __syncthreads();
    for (unsigned int p = t; p < total; p += 256) {
        atomicAdd(&rcnt[(lrec[p].x >> 16) & 127], 1u);
    }
    __syncthreads();
    if (t < BROWS) loff[t] = rcnt[t];
    __syncthreads();
    for (int off = 1; off < BROWS; off <<= 1) {
        unsigned int add = (t >= off && t < BROWS) ? loff[t - off] : 0u;
        __syncthreads();
        if (t < BROWS) loff[t] += add;
        __syncthreads();
    }
    int r0 = b * BROWS;
    int nrows = N_NODES - r0;
    if (nrows > BROWS) nrows = BROWS;
    if (t < BROWS) {
        unsigned int excl = loff[t] - rcnt[t];
        if (t < nrows) rowptr[r0 + t] = lo + (int)excl;
        lcur[t] = (unsigned int)lo + excl;
    }
    if (b == NB - 1 && t == 0) rowptr[N_NODES] = hi;
    __syncthreads();
    for (unsigned int p = t; p < total; p += 256) {
        uint2 rec = lrec[p];
        unsigned int rl = (rec.x >> 16) & 127;
        unsigned int pos = atomicAdd(&lcur[rl], 1u);
        uint2 cw;
        cw.x = rec.x & 0xFFFFu;
        cw.y = rec.y;
        colwS[pos] = cw;
    }
}

// ---------------------------------------------------------------------------
// A(fp16) = x @ W1 via mfma_f32_16x16x32_bf16, split-bf16 3-pass.
__global__ __launch_bounds__(256) void gemm1_k(const float* __restrict__ x,
                                               const unsigned short* __restrict__ wh,
                                               const unsigned short* __restrict__ wl,
                                               __half* __restrict__ Ah) {
    int t = threadIdx.x;
    int w = t >> 6, l = t & 63;
    int row0 = blockIdx.x * 64 + w * 16;
    int arow = row0 + (l & 15);
    if (arow > N_NODES - 1) arow = N_NODES - 1;
    int kbase = (l >> 4) * 8;
    bf16x8 ah[4], al[4];
#pragma unroll
    for (int ks = 0; ks < 4; ++ks) {
        const float* px = &x[arow * D1 + ks * 32 + kbase];
        float4 v0 = *reinterpret_cast<const float4*>(px);
        float4 v1 = *reinterpret_cast<const float4*>(px + 4);
        float vv[8] = {v0.x, v0.y, v0.z, v0.w, v1.x, v1.y, v1.z, v1.w};
#pragma unroll
        for (int j = 0; j < 8; ++j) {
            unsigned short h, lo2;
            bf16_split(vv[j], h, lo2);
            ah[ks][j] = (short)h;
            al[ks][j] = (short)lo2;
        }
    }
    f32x4 acc[8];
#pragma unroll
    for (int nt = 0; nt < 8; ++nt) acc[nt] = (f32x4)(0.f);
#pragma unroll
    for (int nt = 0; nt < 8; ++nt) {
#pragma unroll
        for (int ks = 0; ks < 4; ++ks) {
            int fo = ((nt * 4 + ks) * 64 + l) * 8;
            bf16x8 bh = *reinterpret_cast<const bf16x8*>(&wh[fo]);
            bf16x8 bl = *reinterpret_cast<const bf16x8*>(&wl[fo]);
            acc[nt] = __builtin_amdgcn_mfma_f32_16x16x32_bf16(ah[ks], bh, acc[nt], 0, 0, 0);
            acc[nt] = __builtin_amdgcn_mfma_f32_16x16x32_bf16(ah[ks], bl, acc[nt], 0, 0, 0);
            acc[nt] = __builtin_amdgcn_mfma_f32_16x16x32_bf16(al[ks], bh, acc[nt], 0, 0, 0);
        }
    }
    int crow0 = row0 + (l >> 4) * 4;
    int ccol = l & 15;
#pragma unroll
    for (int nt = 0; nt < 8; ++nt) {
#pragma unroll
        for (int r = 0; r < 4; ++r) {
            int rr = crow0 + r;
            if (rr < N_NODES) Ah[rr * D1 + nt * 16 + ccol] = __float2half_rn(acc[nt][r]);
        }
    }
}

// ---------------------------------------------------------------------------
// Fused spmm1 + gemm2. Gather phase: 16 lanes x 16 B per edge -> 4 edges in
// flight per wave-iteration (2x the MLP of the 32-lane form, same inst count).
// colwS record load is a uniform broadcast within each 16-lane group.
__global__ __launch_bounds__(256) void spmm1g_k(const __half* __restrict__ Ah,
                                                const int* __restrict__ rowptr,
                                                const uint2* __restrict__ colwS,
                                                const float* __restrict__ b1,
                                                const unsigned short* __restrict__ wh,
                                                const unsigned short* __restrict__ wl,
                                                __half* __restrict__ Gh) {
    __shared__ float hrow[16][132];
    int t = threadIdx.x;
    int w = t >> 6, lane = t & 63;
    int q = lane >> 4;      // edge slot 0..3
    int li = lane & 15;     // 16 B group within the 256 B row
    int row0 = blockIdx.x * 16;
#pragma unroll
    for (int i = 0; i < 4; ++i) {
        int r = row0 + w * 4 + i;
        int s = rowptr[r], e = rowptr[r + 1];
        float a0 = 0.f, a1 = 0.f, a2 = 0.f, a3 = 0.f;
        float a4 = 0.f, a5 = 0.f, a6 = 0.f, a7 = 0.f;
#pragma unroll 4
        for (int j = s + q; j < e; j += 4) {
            uint2 cw = colwS[j];
            float wv = __uint_as_float(cw.y);
            uint4 qv = *reinterpret_cast<const uint4*>(&Ah[cw.x * D1 + li * 8]);
            float2 f0 = __half22float2(*reinterpret_cast<const __half2*>(&qv.x));
            float2 f1 = __half22float2(*reinterpret_cast<const __half2*>(&qv.y));
            float2 f2 = __half22float2(*reinterpret_cast<const __half2*>(&qv.z));
            float2 f3 = __half22float2(*reinterpret_cast<const __half2*>(&qv.w));
            a0 += wv * f0.x; a1 += wv * f0.y;
            a2 += wv * f1.x; a3 += wv * f1.y;
            a4 += wv * f2.x; a5 += wv * f2.y;
            a6 += wv * f3.x; a7 += wv * f3.y;
        }
        // reduce across the 4 edge slots (lanes differing in bits 4,5)
        a0 += __shfl_xor(a0, 16); a1 += __shfl_xor(a1, 16);
        a2 += __shfl_xor(a2, 16); a3 += __shfl_xor(a3, 16);
        a4 += __shfl_xor(a4, 16); a5 += __shfl_xor(a5, 16);
        a6 += __shfl_xor(a6, 16); a7 += __shfl_xor(a7, 16);
        a0 += __shfl_xor(a0, 32); a1 += __shfl_xor(a1, 32);
        a2 += __shfl_xor(a2, 32); a3 += __shfl_xor(a3, 32);
        a4 += __shfl_xor(a4, 32); a5 += __shfl_xor(a5, 32);
        a6 += __shfl_xor(a6, 32); a7 += __shfl_xor(a7, 32);
        if (q == 0) {  // lanes 0..15 hold cols li*8 .. li*8+7
            float4 c0 = *reinterpret_cast<const float4*>(&b1[li * 8]);
            float4 c1 = *reinterpret_cast<const float4*>(&b1[li * 8 + 4]);
            float4 h0, h1;
            h0.x = fmaxf(a0 + c0.x, 0.f);
            h0.y = fmaxf(a1 + c0.y, 0.f);
            h0.z = fmaxf(a2 + c0.z, 0.f);
            h0.w = fmaxf(a3 + c0.w, 0.f);
            h1.x = fmaxf(a4 + c1.x, 0.f);
            h1.y = fmaxf(a5 + c1.y, 0.f);
            h1.z = fmaxf(a6 + c1.z, 0.f);
            h1.w = fmaxf(a7 + c1.w, 0.f);
            *reinterpret_cast<float4*>(&hrow[w * 4 + i][li * 8]) = h0;
            *reinterpret_cast<float4*>(&hrow[w * 4 + i][li * 8 + 4]) = h1;
        }
    }
    __syncthreads();
    // MFMA epilogue: wave w computes output n-tile w (cols w*16 .. w*16+15)
    int l = lane;
    int kb = (l >> 4) * 8;
    bf16x8 ah[4], al[4];
#pragma unroll
    for (int ks = 0; ks < 4; ++ks) {
        const float* ph = &hrow[l & 15][ks * 32 + kb];
        float4 v0 = *reinterpret_cast<const float4*>(ph);
        float4 v1 = *reinterpret_cast<const float4*>(ph + 4);
        float vv[8] = {v0.x, v0.y, v0.z, v0.w, v1.x, v1.y, v1.z, v1.w};
#pragma unroll
        for (int j = 0; j < 8; ++j) {
            unsigned short h, lo2;
            bf16_split(vv[j], h, lo2);
            ah[ks][j] = (short)h;
            al[ks][j] = (short)lo2;
        }
    }
    f32x4 acc2 = (f32x4)(0.f);
#pragma unroll
    for (int ks = 0; ks < 4; ++ks) {
        int fo = ((w * 4 + ks) * 64 + l) * 8;
        bf16x8 bh = *reinterpret_cast<const bf16x8*>(&wh[fo]);
        bf16x8 bl = *reinterpret_cast<const bf16x8*>(&wl[fo]);
        acc2 = __builtin_amdgcn_mfma_f32_16x16x32_bf16(ah[ks], bh, acc2, 0, 0, 0);
        acc2 = __builtin_amdgcn_mfma_f32_16x16x32_bf16(ah[ks], bl, acc2, 0, 0, 0);
        acc2 = __builtin_amdgcn_mfma_f32_16x16x32_bf16(al[ks], bh, acc2, 0, 0, 0);
    }
    int crow0 = row0 + (l >> 4) * 4;
    int ccol = w * 16 + (l & 15);
#pragma unroll
    for (int r = 0; r < 4; ++r) {
        Gh[(crow0 + r) * D2P + ccol] = __float2half_rn(acc2[r]);
    }
}

// out[r] = log_softmax(sum_j w_j * G[col_j] + b2) — one row/wave.
// 8 lanes x 16 B per edge -> 8 edges in flight per wave-iteration; the
// Gh row (128 B) is read by one 8-lane group per edge.
__global__ __launch_bounds__(256) void spmm2lsm_k(const __half* __restrict__ Gh,
                                                  const int* __restrict__ rowptr,
                                                  const uint2* __restrict__ colwS,
                                                  const float* __restrict__ b2,
                                                  float* __restrict__ out) {
    int t = threadIdx.x;
    int r = blockIdx.x * 4 + (t >> 6);
    int lane = t & 63;
    int q = lane >> 3;      // edge slot 0..7
    int li = lane & 7;      // 16 B group within the 128 B row
    int s = rowptr[r], e = rowptr[r + 1];
    float a0 = 0.f, a1 = 0.f, a2 = 0.f, a3 = 0.f;
    float a4 = 0.f, a5 = 0.f, a6 = 0.f, a7 = 0.f;
#pragma unroll 4
    for (int j = s + q; j < e; j += 8) {
        uint2 cw = colwS[j];
        float wv = __uint_as_float(cw.y);
        uint4 qv = *reinterpret_cast<const uint4*>(&Gh[cw.x * D2P + li * 8]);
        float2 f0 = __half22float2(*reinterpret_cast<const __half2*>(&qv.x));
        float2 f1 = __half22float2(*reinterpret_cast<const __half2*>(&qv.y));
        float2 f2 = __half22float2(*reinterpret_cast<const __half2*>(&qv.z));
        float2 f3 = __half22float2(*reinterpret_cast<const __half2*>(&qv.w));
        a0 += wv * f0.x; a1 += wv * f0.y;
        a2 += wv * f1.x; a3 += wv * f1.y;
        a4 += wv * f2.x; a5 += wv * f2.y;
        a6 += wv * f3.x; a7 += wv * f3.y;
    }
    // reduce across the 8 edge slots (lanes differing in bits 3,4,5)
    a0 += __shfl_xor(a0, 8);  a1 += __shfl_xor(a1, 8);
    a2 += __shfl_xor(a2, 8);  a3 += __shfl_xor(a3, 8);
    a4 += __shfl_xor(a4, 8);  a5 += __shfl_xor(a5, 8);
    a6 += __shfl_xor(a6, 8);  a7 += __shfl_xor(a7, 8);
    a0 += __shfl_xor(a0, 16); a1 += __shfl_xor(a1, 16);
    a2 += __shfl_xor(a2, 16); a3 += __shfl_xor(a3, 16);
    a4 += __shfl_xor(a4, 16); a5 += __shfl_xor(a5, 16);
    a6 += __shfl_xor(a6, 16); a7 += __shfl_xor(a7, 16);
    a0 += __shfl_xor(a0, 32); a1 += __shfl_xor(a1, 32);
    a2 += __shfl_xor(a2, 32); a3 += __shfl_xor(a3, 32);
    a4 += __shfl_xor(a4, 32); a5 += __shfl_xor(a5, 32);
    a6 += __shfl_xor(a6, 32); a7 += __shfl_xor(a7, 32);
    // lanes 0..7 (q==0) hold cols li*8 .. li*8+7; cols >= 40 are padding
    bool valid = (lane < 8) && (li < 5);
    float v[8];
    if (valid) {
        v[0] = a0 + b2[li * 8 + 0];
        v[1] = a1 + b2[li * 8 + 1];
        v[2] = a2 + b2[li * 8 + 2];
        v[3] = a3 + b2[li * 8 + 3];
        v[4] = a4 + b2[li * 8 + 4];
        v[5] = a5 + b2[li * 8 + 5];
        v[6] = a6 + b2[li * 8 + 6];
        v[7] = a7 + b2[li * 8 + 7];
    } else {
#pragma unroll
        for (int k = 0; k < 8; ++k) v[k] = -INFINITY;
    }
    float m = v[0];
#pragma unroll
    for (int k = 1; k < 8; ++k) m = fmaxf(m, v[k]);
    m = fmaxf(m, __shfl_xor(m, 1));
    m = fmaxf(m, __shfl_xor(m, 2));
    m = fmaxf(m, __shfl_xor(m, 4));
    float ex = 0.f;
    if (valid) {
#pragma unroll
        for (int k = 0; k < 8; ++k) ex += expf(v[k] - m);
    }
    ex += __shfl_xor(ex, 1);
    ex += __shfl_xor(ex, 2);
    ex += __shfl_xor(ex, 4);
    float lse = m + logf(ex);
    if (valid) {
        float4 o0, o1;
        o0.x = v[0] - lse; o0.y = v[1] - lse; o0.z = v[2] - lse; o0.w = v[3] - lse;
        o1.x = v[4] - lse; o1.y = v[5] - lse; o1.z = v[6] - lse; o1.w = v[7] - lse;
        *reinterpret_cast<float4*>(&out[r * D2 + li * 8]) = o0;
        *reinterpret_cast<float4*>(&out[r * D2 + li * 8 + 4]) = o1;
    }
}

// ---------------------------------------------------------------------------
extern "C" void kernel_launch(void* const* d_in, const int* in_sizes, int n_in,
                              void* d_out, int out_size, void* d_ws, size_t ws_size,
                              hipStream_t stream) {
    const float* x = (const float*)d_in[0];
    const unsigned int* ei = (const unsigned int*)d_in[1];
    const float* ew = (const float*)d_in[2];
    const float* W1 = (const float*)d_in[3];
    const float* b1 = (const float*)d_in[4];
    const float* W2 = (const float*)d_in[5];
    const float* b2 = (const float*)d_in[6];
    float* out = (float*)d_out;

    char* w = (char*)d_ws;
    __half* Ah = (__half*)w;                                // 12.8 MB  fp16 x@W1
    uint2* tmp8 = (uint2*)(w + 12800000);                   // 12.8 MB  chunk-sorted records
    __half* Gh = (__half*)(w + 25600000);                   // 6.4 MB   fp16 [N][64]
    uint2* colwS = (uint2*)(w + 32000000);                  // 12.8 MB  CSR {col,w}
    int* rowptr = (int*)(w + 44800000);                     // (N+1)*4
    unsigned int* bofs = (unsigned int*)(w + 45000064);     // 256*(NB+1)*4 = 401408
    unsigned int* gbhp = (unsigned int*)(w + 45401472);     // NB*64
    unsigned short* wh1 = (unsigned short*)(w + 45426496);  // 32 KB
    unsigned short* wl1 = (unsigned short*)(w + 45459264);  // 32 KB
    unsigned short* wh2 = (unsigned short*)(w + 45492032);  // 16 KB
    unsigned short* wl2 = (unsigned short*)(w + 45508416);  // 16 KB

    prep_k<<<121, 256, 0, stream>>>(W1, wh1, wl1, W2, wh2, wl2, gbhp);
    bin_k<<<256, 256, 0, stream>>>(ei, ew, gbhp, tmp8, bofs);
    gemm1_k<<<782, 256, 0, stream>>>(x, wh1, wl1, Ah);
    csr_k<<<NB, 256, 0, stream>>>(tmp8, bofs, gbhp, rowptr, colwS);

    spmm1g_k<<<N_NODES / 16, 256, 0, stream>>>(Ah, rowptr, colwS, b1, wh2, wl2, Gh);
    spmm2lsm_k<<<N_NODES / 4, 256, 0, stream>>>(Gh, rowptr, colwS, b2, out);
}